// Round 4
// baseline (259.417 us; speedup 1.0000x reference)
//
#include <hip/hip_runtime.h>
#include <hip/hip_bf16.h>
#include <math.h>

// Problem constants (fixed by setup_inputs)
#define BS     8
#define LQ     1000
#define DMODEL 256
#define NH     8
#define NLV    4
#define NPT    4
#define LEN_V  8500          // 80*80+40*40+20*20+10*10
#define NQ     (BS*LQ)       // 8000
#define MV     (BS*LEN_V)    // 68000
#define KS     8             // K=256 / 32 per mfma step

typedef __attribute__((ext_vector_type(8))) short short8;     // 8 bf16 (4 VGPRs)
typedef __attribute__((ext_vector_type(4))) float floatx4;

static __device__ __forceinline__ unsigned short f2bf(float f) {
    __hip_bfloat16 h = __float2bfloat16(f);   // RNE
    return __builtin_bit_cast(unsigned short, h);
}
static __device__ __forceinline__ float asf(unsigned int u) {
    return __builtin_bit_cast(float, u);
}

// ---------------------------------------------------------------------------
// Fragment-layout MFMA GEMM, no LDS. C[M,N] = A[M,256] @ B[256,N] + bias.
//   A: row-major (bf16 if A_BF16 else fp32, converted in-register).
//   ALL A fragments for the full K=256 are prefetched into registers
//   (8 s-steps x 4 row-tiles x short8 = 128 VGPRs) so the K-loop has no
//   global-latency dependence; __launch_bounds__(256,2) caps at 256 VGPRs.
//   B: pre-shuffled fragment layout: chunk (u = n/16, s = k/32):
//        elem(lane l, j) = B[s*32 + (l>>4)*8 + j][u*16 + (l&15)]
//   Block = 256 thr = 4 waves (2x2), wave tile 64x64 = 4x4 mfma_16x16x32.
// ---------------------------------------------------------------------------
template <bool A_BF16, bool OUT_BF16>
__global__ __launch_bounds__(256, 2) void mfma_gemm(
    const void* __restrict__ Aptr, const unsigned short* __restrict__ Bfrag,
    const float* __restrict__ bias1, const float* __restrict__ bias2, int nsplit,
    void* __restrict__ Cptr, int M, int N)
{
    const int tid = threadIdx.x;
    const int l   = tid & 63;
    const int w   = tid >> 6;
    const int wm  = w & 1, wn = w >> 1;
    const int bm  = blockIdx.x, bn = blockIdx.y;
    const int lm  = l & 15;   // A row-in-tile / D col
    const int lk  = l >> 4;   // k-quad

    const int Tmax = M / 16 - 1;      // M is always a multiple of 16
    int trow[4];
    #pragma unroll
    for (int i = 0; i < 4; ++i) {
        int t = bm * 8 + wm * 4 + i;
        trow[i] = (t > Tmax) ? Tmax : t;   // clamp: loads stay in-bounds, stores guarded
    }

    const unsigned short* Abf = (const unsigned short*)Aptr;
    const float*          Af  = (const float*)Aptr;

    // ---- prefetch ALL A fragments for K=256 into registers ----
    short8 afr[KS][4];
    #pragma unroll
    for (int s = 0; s < KS; ++s) {
        const int kof = s * 32 + lk * 8;
        #pragma unroll
        for (int i = 0; i < 4; ++i) {
            const int row = trow[i] * 16 + lm;
            if (A_BF16) {
                afr[s][i] = *(const short8*)(Abf + (size_t)row * 256 + kof);
            } else {
                const float* pa = Af + (size_t)row * 256 + kof;
                float4 lo = *(const float4*)pa;
                float4 hi = *(const float4*)(pa + 4);
                short8 t;
                t[0] = (short)f2bf(lo.x); t[1] = (short)f2bf(lo.y);
                t[2] = (short)f2bf(lo.z); t[3] = (short)f2bf(lo.w);
                t[4] = (short)f2bf(hi.x); t[5] = (short)f2bf(hi.y);
                t[6] = (short)f2bf(hi.z); t[7] = (short)f2bf(hi.w);
                afr[s][i] = t;
            }
        }
    }

    floatx4 acc[4][4];
    #pragma unroll
    for (int i = 0; i < 4; ++i)
        #pragma unroll
        for (int j = 0; j < 4; ++j)
            #pragma unroll
            for (int r = 0; r < 4; ++r) acc[i][j][r] = 0.f;

    const int u0 = bn * 8 + wn * 4;

    #pragma unroll
    for (int s = 0; s < KS; ++s) {
        short8 bfr[4];
        #pragma unroll
        for (int j = 0; j < 4; ++j)
            bfr[j] = *(const short8*)(Bfrag + ((size_t)((u0 + j) * KS + s) * 64 + l) * 8);

        #pragma unroll
        for (int i = 0; i < 4; ++i)
            #pragma unroll
            for (int j = 0; j < 4; ++j)
                acc[i][j] = __builtin_amdgcn_mfma_f32_16x16x32_bf16(
                                afr[s][i], bfr[j], acc[i][j], 0, 0, 0);
    }

    #pragma unroll
    for (int j = 0; j < 4; ++j) {
        const int col = bn * 128 + wn * 64 + j * 16 + lm;
        const float bv = (bias2 != nullptr && col >= nsplit) ? bias2[col - nsplit]
                                                             : bias1[col];
        #pragma unroll
        for (int i = 0; i < 4; ++i) {
            const int rbase = (bm * 8 + wm * 4 + i) * 16 + lk * 4;  // true rows
            #pragma unroll
            for (int r = 0; r < 4; ++r) {
                const int row = rbase + r;
                if (row < M) {
                    const float v = acc[i][j][r] + bv;
                    if (OUT_BF16)
                        ((unsigned short*)Cptr)[(size_t)row * N + col] = f2bf(v);
                    else
                        ((float*)Cptr)[(size_t)row * N + col] = v;
                }
            }
        }
    }
}

// ------------------- weights -> bf16 fragment layout (one-shot) -------------------
__global__ __launch_bounds__(256) void wtransform(
    const float* __restrict__ w_v, const float* __restrict__ w_off,
    const float* __restrict__ w_attn, const float* __restrict__ w_o,
    unsigned short* __restrict__ wv_f, unsigned short* __restrict__ woa_f,
    unsigned short* __restrict__ wo_f)
{
    const int gid = blockIdx.x * 256 + threadIdx.x;   // 28672 total, grid exact
    int chunk, mode;
    if (gid < 8192)               { chunk = gid;         mode = 0; }
    else if (gid < 8192 + 12288)  { chunk = gid - 8192;  mode = 1; }
    else                          { chunk = gid - 20480; mode = 2; }
    const int l = chunk & 63, s = (chunk >> 6) & 7, u = chunk >> 9;
    short8 o;
    #pragma unroll
    for (int j = 0; j < 8; ++j) {
        const int k = s * 32 + (l >> 4) * 8 + j;
        const int n = u * 16 + (l & 15);
        float v;
        if (mode == 0)      v = w_v[k * 256 + n];
        else if (mode == 1) v = (n < 256) ? w_off[k * 256 + n] : w_attn[k * 128 + (n - 256)];
        else                v = w_o[k * 256 + n];
        o[j] = (short)f2bf(v);
    }
    unsigned short* dp = (mode == 0 ? wv_f : mode == 1 ? woa_f : wo_f)
                         + ((size_t)(u * 8 + s) * 64 + l) * 8;
    *(short8*)dp = o;
}

// ---------------- softmax + bilinear sampling + head weighting ----------------
// 8 queries per block, 1000 blocks. thread = (q8 = tid>>5, h = (tid>>2)&7,
// oct = tid&3). Each thread accumulates 8 channels (16-B short8 gathers).
// Branchless corners: clamped index + validity folded into weight.
__global__ __launch_bounds__(256) void ms_sample(
    const unsigned short* __restrict__ v,    // [BS,8500,256] bf16
    const float* __restrict__ offattn,       // [NQ,384]: offs[0:256) | logits[256:384)
    const float* __restrict__ refp,          // [NQ,4,2]
    unsigned short* __restrict__ out_pre)    // [NQ,256] bf16
{
    __shared__ float offx_s[8][16][8];   // [q][lvl*4+p][h] — h on distinct banks
    __shared__ float offy_s[8][16][8];
    __shared__ float atw_s [8][16][8];
    __shared__ float ref_s [8][8];

    const int tid = threadIdx.x;
    const int iq0 = blockIdx.x * 8;

    if (tid < 64) {
        const int q = tid >> 3, h = tid & 7;
        const float* rowp = offattn + (size_t)(iq0 + q) * 384;
        float lg[16];
        float m = -1e30f;
        #pragma unroll
        for (int i = 0; i < 16; ++i) { lg[i] = rowp[256 + h * 16 + i]; m = fmaxf(m, lg[i]); }
        float s = 0.f;
        #pragma unroll
        for (int i = 0; i < 16; ++i) { lg[i] = __expf(lg[i] - m); s += lg[i]; }
        const float inv = 1.f / s;
        #pragma unroll
        for (int i = 0; i < 16; ++i) atw_s[q][i][h] = lg[i] * inv;
        #pragma unroll
        for (int i = 0; i < 16; ++i) {
            offx_s[q][i][h] = rowp[(h * 16 + i) * 2 + 0];
            offy_s[q][i][h] = rowp[(h * 16 + i) * 2 + 1];
        }
        if (h == 0) {
            #pragma unroll
            for (int i = 0; i < 8; ++i) ref_s[q][i] = refp[(size_t)(iq0 + q) * 8 + i];
        }
    }
    __syncthreads();

    const int q8  = tid >> 5;
    const int sub = tid & 31;
    const int h   = sub >> 2;
    const int oct = sub & 3;
    const int iq  = iq0 + q8;
    const int b   = iq / LQ;             // 8 | LQ, whole block same batch

    float acc[8] = {0.f, 0.f, 0.f, 0.f, 0.f, 0.f, 0.f, 0.f};
    const unsigned short* vb = v + (size_t)b * LEN_V * 256 + h * 32 + oct * 8;
    const int Hs[4] = {80, 40, 20, 10};
    const int st[4] = {0, 6400, 8000, 8400};

    #pragma unroll
    for (int lvl = 0; lvl < NLV; ++lvl) {
        const int W = Hs[lvl];
        const float bx = ref_s[q8][lvl * 2 + 0] * (float)W - 0.5f;
        const float by = ref_s[q8][lvl * 2 + 1] * (float)W - 0.5f;
        const unsigned short* vl = vb + (size_t)st[lvl] * 256;
        #pragma unroll
        for (int p = 0; p < NPT; ++p) {
            const int lp = lvl * 4 + p;
            const float x  = bx + offx_s[q8][lp][h];
            const float y  = by + offy_s[q8][lp][h];
            const float at = atw_s[q8][lp][h];
            const float x0f = floorf(x), y0f = floorf(y);
            const float fx = x - x0f, fy = y - y0f;
            const int x0 = (int)x0f, y0 = (int)y0f;
            const int x1 = x0 + 1,   y1 = y0 + 1;
            const int cx0 = min(max(x0, 0), W - 1);
            const int cx1 = min(max(x1, 0), W - 1);
            const int cy0 = min(max(y0, 0), W - 1);
            const int cy1 = min(max(y1, 0), W - 1);
            const float vx0 = (x0 >= 0 && x0 < W) ? 1.f : 0.f;
            const float vx1 = (x1 >= 0 && x1 < W) ? 1.f : 0.f;
            const float vy0 = (y0 >= 0 && y0 < W) ? 1.f : 0.f;
            const float vy1 = (y1 >= 0 && y1 < W) ? 1.f : 0.f;
            const float w00 = at * (1.f - fx) * (1.f - fy) * vx0 * vy0;
            const float w01 = at * fx * (1.f - fy) * vx1 * vy0;
            const float w10 = at * (1.f - fx) * fy * vx0 * vy1;
            const float w11 = at * fx * fy * vx1 * vy1;
            const unsigned short* r0 = vl + (size_t)(cy0 * W) * 256;
            const unsigned short* r1 = vl + (size_t)(cy1 * W) * 256;
            const uint4 d00 = *(const uint4*)(r0 + (size_t)cx0 * 256);
            const uint4 d01 = *(const uint4*)(r0 + (size_t)cx1 * 256);
            const uint4 d10 = *(const uint4*)(r1 + (size_t)cx0 * 256);
            const uint4 d11 = *(const uint4*)(r1 + (size_t)cx1 * 256);
            acc[0] += w00 * asf(d00.x << 16) + w01 * asf(d01.x << 16)
                    + w10 * asf(d10.x << 16) + w11 * asf(d11.x << 16);
            acc[1] += w00 * asf(d00.x & 0xffff0000u) + w01 * asf(d01.x & 0xffff0000u)
                    + w10 * asf(d10.x & 0xffff0000u) + w11 * asf(d11.x & 0xffff0000u);
            acc[2] += w00 * asf(d00.y << 16) + w01 * asf(d01.y << 16)
                    + w10 * asf(d10.y << 16) + w11 * asf(d11.y << 16);
            acc[3] += w00 * asf(d00.y & 0xffff0000u) + w01 * asf(d01.y & 0xffff0000u)
                    + w10 * asf(d10.y & 0xffff0000u) + w11 * asf(d11.y & 0xffff0000u);
            acc[4] += w00 * asf(d00.z << 16) + w01 * asf(d01.z << 16)
                    + w10 * asf(d10.z << 16) + w11 * asf(d11.z << 16);
            acc[5] += w00 * asf(d00.z & 0xffff0000u) + w01 * asf(d01.z & 0xffff0000u)
                    + w10 * asf(d10.z & 0xffff0000u) + w11 * asf(d11.z & 0xffff0000u);
            acc[6] += w00 * asf(d00.w << 16) + w01 * asf(d01.w << 16)
                    + w10 * asf(d10.w << 16) + w11 * asf(d11.w << 16);
            acc[7] += w00 * asf(d00.w & 0xffff0000u) + w01 * asf(d01.w & 0xffff0000u)
                    + w10 * asf(d10.w & 0xffff0000u) + w11 * asf(d11.w & 0xffff0000u);
        }
    }

    short8 o;
    #pragma unroll
    for (int j = 0; j < 8; ++j) o[j] = (short)f2bf(acc[j]);
    *(short8*)(out_pre + (size_t)iq * 256 + sub * 8) = o;
}

// ------------------------------- launcher -------------------------------
extern "C" void kernel_launch(void* const* d_in, const int* in_sizes, int n_in,
                              void* d_out, int out_size, void* d_ws, size_t ws_size,
                              hipStream_t stream)
{
    const float* query  = (const float*)d_in[0];
    const float* refp   = (const float*)d_in[1];
    const float* value  = (const float*)d_in[2];
    const float* w_off  = (const float*)d_in[3];
    const float* b_off  = (const float*)d_in[4];
    const float* w_attn = (const float*)d_in[5];
    const float* b_attn = (const float*)d_in[6];
    const float* w_v    = (const float*)d_in[7];
    const float* b_v    = (const float*)d_in[8];
    const float* w_o    = (const float*)d_in[9];
    const float* b_o    = (const float*)d_in[10];
    (void)d_in[11]; (void)d_in[12];  // shapes/starts fixed by problem, hardcoded

    float* out = (float*)d_out;

    // workspace layout (bytes, 16B-aligned)
    char* ws = (char*)d_ws;
    unsigned short* v_proj  = (unsigned short*)ws;                    // 34,816,000
    float*          offattn = (float*)(ws + 34816000);                // 12,288,000
    unsigned short* outpre  = (unsigned short*)(ws + 47104000);       //  4,096,000
    unsigned short* wv_f    = (unsigned short*)(ws + 51200000);       //    131,072
    unsigned short* woa_f   = (unsigned short*)(ws + 51331072);       //    196,608
    unsigned short* wo_f    = (unsigned short*)(ws + 51527680);       //    131,072  (end 51,658,752)

    dim3 blk(256);

    hipLaunchKernelGGL(wtransform, dim3(112), blk, 0, stream,
                       w_v, w_off, w_attn, w_o, wv_f, woa_f, wo_f);
    // v_proj = value @ w_v + b_v  (fp32 A fused-cast, bf16 out)  [68000 x 256]
    hipLaunchKernelGGL((mfma_gemm<false, true>), dim3(532, 2), blk, 0, stream,
                       value, wv_f, b_v, nullptr, 1 << 30, v_proj, MV, 256);
    // offattn = query @ [w_off | w_attn] + bias  (fp32 out)  [8000 x 384]
    hipLaunchKernelGGL((mfma_gemm<false, false>), dim3(63, 3), blk, 0, stream,
                       query, woa_f, b_off, b_attn, 256, offattn, NQ, 384);
    // sampling + softmax + head weighting -> out_pre bf16  [8000 x 256]
    hipLaunchKernelGGL(ms_sample, dim3(1000), blk, 0, stream,
                       v_proj, offattn, refp, outpre);
    // out = out_pre @ w_o + b_o  [8000 x 256] fp32
    hipLaunchKernelGGL((mfma_gemm<true, false>), dim3(63, 2), blk, 0, stream,
                       outpre, wo_f, b_o, nullptr, 1 << 30, out, NQ, 256);
}

// Round 6
// 231.862 us; speedup vs baseline: 1.1188x; 1.1188x over previous
//
#include <hip/hip_runtime.h>
#include <hip/hip_bf16.h>
#include <math.h>

// Problem constants (fixed by setup_inputs)
#define BS     8
#define LQ     1000
#define DMODEL 256
#define NH     8
#define NLV    4
#define NPT    4
#define LEN_V  8500          // 80*80+40*40+20*20+10*10
#define NQ     (BS*LQ)       // 8000
#define MV     (BS*LEN_V)    // 68000
#define KS     8             // K=256 / 32 per mfma step
#define LDA    264           // LDS row stride (bf16 elems): 256 + 8 pad -> 2-way (free)

typedef __attribute__((ext_vector_type(8))) short short8;     // 8 bf16 (4 VGPRs)
typedef __attribute__((ext_vector_type(4))) float floatx4;

static __device__ __forceinline__ unsigned short f2bf(float f) {
    __hip_bfloat16 h = __float2bfloat16(f);   // RNE
    return __builtin_bit_cast(unsigned short, h);
}
static __device__ __forceinline__ float asf(unsigned int u) {
    return __builtin_bit_cast(float, u);
}

// ---------------------------------------------------------------------------
// LDS-staged MFMA GEMM. C[M, N] = A[M,256] @ B[256,N] + bias, N = gridDim.y*128.
//   - B fragments for this block's 128-col strip are loaded ONCE into 128 VGPRs
//     before a grid-stride loop over 128-row M-tiles (loop-invariant -> hoisted).
//   - Each M-tile: A staged to LDS as bf16 (fp32 converted in-register), rows
//     padded to 264 so both ds_write and ds_read are conflict-free; one barrier;
//     K-loop is pure ds_read_b128 + MFMA (compiler cannot sink past s_barrier).
//   - 256 thr = 4 waves (2x2), wave tile 64x64 = 4x4 mfma_16x16x32.
//   - LDS 67,584 B -> 2 blocks/CU; __launch_bounds__(256,2) -> 256 VGPR cap.
// ---------------------------------------------------------------------------
template <bool A_BF16, bool OUT_BF16>
__global__ __launch_bounds__(256, 2) void mfma_gemm_lds(
    const void* __restrict__ Aptr, const unsigned short* __restrict__ Bfrag,
    const float* __restrict__ bias1, const float* __restrict__ bias2, int nsplit,
    void* __restrict__ Cptr, int M)
{
    __shared__ unsigned short As[128 * LDA];   // 67,584 bytes

    const int tid = threadIdx.x;
    const int l   = tid & 63;
    const int w   = tid >> 6;
    const int wm  = w & 1, wn = w >> 1;
    const int bn  = blockIdx.y;
    const int lm  = l & 15;   // A row-in-frag / C col
    const int lk  = l >> 4;   // k-quad / C row-quad
    const int N   = (int)gridDim.y * 128;
    const int n_mtiles = (M + 127) >> 7;

    // ---- B fragments for cols [bn*128, bn*128+128): loop-invariant registers ----
    short8 Bf[4][KS];
    const int u0 = bn * 8 + wn * 4;
    #pragma unroll
    for (int j = 0; j < 4; ++j)
        #pragma unroll
        for (int s = 0; s < KS; ++s)
            Bf[j][s] = *(const short8*)(Bfrag + ((size_t)((u0 + j) * KS + s) * 64 + l) * 8);

    for (int bm = blockIdx.x; bm < n_mtiles; bm += gridDim.x) {
        // ---- stage A tile (128 rows x 256 k) -> LDS bf16, padded rows ----
        if (A_BF16) {
            const unsigned short* Ab = (const unsigned short*)Aptr;
            #pragma unroll
            for (int j = 0; j < 16; ++j) {            // 16*256 = 4096 short8 = full tile
                const int vi  = j * 256 + tid;        // 16B-vec index in tile
                const int row = vi >> 5;              // 32 short8 per 256-elem row
                const int col = (vi & 31) * 8;
                int grow = bm * 128 + row; grow = grow < M ? grow : M - 1;
                short8 v = *(const short8*)(Ab + (size_t)grow * 256 + col);
                *(short8*)(&As[row * LDA + col]) = v;
            }
        } else {
            const float* Af = (const float*)Aptr;
            #pragma unroll
            for (int j = 0; j < 32; ++j) {            // 32*256 = 8192 float4 = full tile
                const int vi  = j * 256 + tid;        // float4 index in tile
                const int row = vi >> 6;              // 64 float4 per 256-elem row
                const int col = (vi & 63) * 4;
                int grow = bm * 128 + row; grow = grow < M ? grow : M - 1;
                float4 f = *(const float4*)(Af + (size_t)grow * 256 + col);
                ushort4 h;
                h.x = f2bf(f.x); h.y = f2bf(f.y); h.z = f2bf(f.z); h.w = f2bf(f.w);
                *(ushort4*)(&As[row * LDA + col]) = h;
            }
        }
        __syncthreads();

        // ---- K-loop: pure LDS + MFMA ----
        floatx4 acc[4][4];
        #pragma unroll
        for (int i = 0; i < 4; ++i)
            #pragma unroll
            for (int j = 0; j < 4; ++j)
                #pragma unroll
                for (int r = 0; r < 4; ++r) acc[i][j][r] = 0.f;

        #pragma unroll
        for (int s = 0; s < KS; ++s) {
            short8 afr[4];
            #pragma unroll
            for (int i = 0; i < 4; ++i) {
                const int r = wm * 64 + i * 16 + lm;
                afr[i] = *(const short8*)(&As[r * LDA + s * 32 + lk * 8]);
            }
            #pragma unroll
            for (int i = 0; i < 4; ++i)
                #pragma unroll
                for (int j = 0; j < 4; ++j)
                    acc[i][j] = __builtin_amdgcn_mfma_f32_16x16x32_bf16(
                                    afr[i], Bf[j][s], acc[i][j], 0, 0, 0);
        }

        // ---- epilogue: bias + store (C layout: col=lane&15, row=lk*4+r) ----
        #pragma unroll
        for (int j = 0; j < 4; ++j) {
            const int col = bn * 128 + wn * 64 + j * 16 + lm;
            const float bv = (bias2 != nullptr && col >= nsplit) ? bias2[col - nsplit]
                                                                 : bias1[col];
            #pragma unroll
            for (int i = 0; i < 4; ++i) {
                const int rbase = bm * 128 + wm * 64 + i * 16 + lk * 4;
                #pragma unroll
                for (int r = 0; r < 4; ++r) {
                    const int row = rbase + r;
                    if (row < M) {
                        const float v = acc[i][j][r] + bv;
                        if (OUT_BF16)
                            ((unsigned short*)Cptr)[(size_t)row * N + col] = f2bf(v);
                        else
                            ((float*)Cptr)[(size_t)row * N + col] = v;
                    }
                }
            }
        }
        __syncthreads();   // protect LDS before next tile's staging
    }
}

// ------------------- weights -> bf16 fragment layout (one-shot) -------------------
__global__ __launch_bounds__(256) void wtransform(
    const float* __restrict__ w_v, const float* __restrict__ w_off,
    const float* __restrict__ w_attn, const float* __restrict__ w_o,
    unsigned short* __restrict__ wv_f, unsigned short* __restrict__ woa_f,
    unsigned short* __restrict__ wo_f)
{
    const int gid = blockIdx.x * 256 + threadIdx.x;   // 28672 total, grid exact
    int chunk, mode;
    if (gid < 8192)               { chunk = gid;         mode = 0; }
    else if (gid < 8192 + 12288)  { chunk = gid - 8192;  mode = 1; }
    else                          { chunk = gid - 20480; mode = 2; }
    const int l = chunk & 63, s = (chunk >> 6) & 7, u = chunk >> 9;
    short8 o;
    #pragma unroll
    for (int j = 0; j < 8; ++j) {
        const int k = s * 32 + (l >> 4) * 8 + j;
        const int n = u * 16 + (l & 15);
        float v;
        if (mode == 0)      v = w_v[k * 256 + n];
        else if (mode == 1) v = (n < 256) ? w_off[k * 256 + n] : w_attn[k * 128 + (n - 256)];
        else                v = w_o[k * 256 + n];
        o[j] = (short)f2bf(v);
    }
    unsigned short* dp = (mode == 0 ? wv_f : mode == 1 ? woa_f : wo_f)
                         + ((size_t)(u * 8 + s) * 64 + l) * 8;
    *(short8*)dp = o;
}

// ---------------- softmax + bilinear sampling + head weighting ----------------
// 8 queries per block, 1000 blocks. thread = (q8 = tid>>5, h = (tid>>2)&7,
// oct = tid&3). Each thread accumulates 8 channels (16-B short8 gathers).
// Branchless corners: clamped index + validity folded into weight.
__global__ __launch_bounds__(256) void ms_sample(
    const unsigned short* __restrict__ v,    // [BS,8500,256] bf16
    const float* __restrict__ offattn,       // [NQ,384]: offs[0:256) | logits[256:384)
    const float* __restrict__ refp,          // [NQ,4,2]
    unsigned short* __restrict__ out_pre)    // [NQ,256] bf16
{
    __shared__ float offx_s[8][16][8];   // [q][lvl*4+p][h] — h on distinct banks
    __shared__ float offy_s[8][16][8];
    __shared__ float atw_s [8][16][8];
    __shared__ float ref_s [8][8];

    const int tid = threadIdx.x;
    const int iq0 = blockIdx.x * 8;

    if (tid < 64) {
        const int q = tid >> 3, h = tid & 7;
        const float* rowp = offattn + (size_t)(iq0 + q) * 384;
        float lg[16];
        float m = -1e30f;
        #pragma unroll
        for (int i = 0; i < 16; ++i) { lg[i] = rowp[256 + h * 16 + i]; m = fmaxf(m, lg[i]); }
        float s = 0.f;
        #pragma unroll
        for (int i = 0; i < 16; ++i) { lg[i] = __expf(lg[i] - m); s += lg[i]; }
        const float inv = 1.f / s;
        #pragma unroll
        for (int i = 0; i < 16; ++i) atw_s[q][i][h] = lg[i] * inv;
        #pragma unroll
        for (int i = 0; i < 16; ++i) {
            offx_s[q][i][h] = rowp[(h * 16 + i) * 2 + 0];
            offy_s[q][i][h] = rowp[(h * 16 + i) * 2 + 1];
        }
        if (h == 0) {
            #pragma unroll
            for (int i = 0; i < 8; ++i) ref_s[q][i] = refp[(size_t)(iq0 + q) * 8 + i];
        }
    }
    __syncthreads();

    const int q8  = tid >> 5;
    const int sub = tid & 31;
    const int h   = sub >> 2;
    const int oct = sub & 3;
    const int iq  = iq0 + q8;
    const int b   = iq / LQ;             // 8 | LQ, whole block same batch

    float acc[8] = {0.f, 0.f, 0.f, 0.f, 0.f, 0.f, 0.f, 0.f};
    const unsigned short* vb = v + (size_t)b * LEN_V * 256 + h * 32 + oct * 8;
    const int Hs[4] = {80, 40, 20, 10};
    const int st[4] = {0, 6400, 8000, 8400};

    #pragma unroll
    for (int lvl = 0; lvl < NLV; ++lvl) {
        const int W = Hs[lvl];
        const float bx = ref_s[q8][lvl * 2 + 0] * (float)W - 0.5f;
        const float by = ref_s[q8][lvl * 2 + 1] * (float)W - 0.5f;
        const unsigned short* vl = vb + (size_t)st[lvl] * 256;
        #pragma unroll
        for (int p = 0; p < NPT; ++p) {
            const int lp = lvl * 4 + p;
            const float x  = bx + offx_s[q8][lp][h];
            const float y  = by + offy_s[q8][lp][h];
            const float at = atw_s[q8][lp][h];
            const float x0f = floorf(x), y0f = floorf(y);
            const float fx = x - x0f, fy = y - y0f;
            const int x0 = (int)x0f, y0 = (int)y0f;
            const int x1 = x0 + 1,   y1 = y0 + 1;
            const int cx0 = min(max(x0, 0), W - 1);
            const int cx1 = min(max(x1, 0), W - 1);
            const int cy0 = min(max(y0, 0), W - 1);
            const int cy1 = min(max(y1, 0), W - 1);
            const float vx0 = (x0 >= 0 && x0 < W) ? 1.f : 0.f;
            const float vx1 = (x1 >= 0 && x1 < W) ? 1.f : 0.f;
            const float vy0 = (y0 >= 0 && y0 < W) ? 1.f : 0.f;
            const float vy1 = (y1 >= 0 && y1 < W) ? 1.f : 0.f;
            const float w00 = at * (1.f - fx) * (1.f - fy) * vx0 * vy0;
            const float w01 = at * fx * (1.f - fy) * vx1 * vy0;
            const float w10 = at * (1.f - fx) * fy * vx0 * vy1;
            const float w11 = at * fx * fy * vx1 * vy1;
            const unsigned short* r0 = vl + (size_t)(cy0 * W) * 256;
            const unsigned short* r1 = vl + (size_t)(cy1 * W) * 256;
            const uint4 d00 = *(const uint4*)(r0 + (size_t)cx0 * 256);
            const uint4 d01 = *(const uint4*)(r0 + (size_t)cx1 * 256);
            const uint4 d10 = *(const uint4*)(r1 + (size_t)cx0 * 256);
            const uint4 d11 = *(const uint4*)(r1 + (size_t)cx1 * 256);
            acc[0] += w00 * asf(d00.x << 16) + w01 * asf(d01.x << 16)
                    + w10 * asf(d10.x << 16) + w11 * asf(d11.x << 16);
            acc[1] += w00 * asf(d00.x & 0xffff0000u) + w01 * asf(d01.x & 0xffff0000u)
                    + w10 * asf(d10.x & 0xffff0000u) + w11 * asf(d11.x & 0xffff0000u);
            acc[2] += w00 * asf(d00.y << 16) + w01 * asf(d01.y << 16)
                    + w10 * asf(d10.y << 16) + w11 * asf(d11.y << 16);
            acc[3] += w00 * asf(d00.y & 0xffff0000u) + w01 * asf(d01.y & 0xffff0000u)
                    + w10 * asf(d10.y & 0xffff0000u) + w11 * asf(d11.y & 0xffff0000u);
            acc[4] += w00 * asf(d00.z << 16) + w01 * asf(d01.z << 16)
                    + w10 * asf(d10.z << 16) + w11 * asf(d11.z << 16);
            acc[5] += w00 * asf(d00.z & 0xffff0000u) + w01 * asf(d01.z & 0xffff0000u)
                    + w10 * asf(d10.z & 0xffff0000u) + w11 * asf(d11.z & 0xffff0000u);
            acc[6] += w00 * asf(d00.w << 16) + w01 * asf(d01.w << 16)
                    + w10 * asf(d10.w << 16) + w11 * asf(d11.w << 16);
            acc[7] += w00 * asf(d00.w & 0xffff0000u) + w01 * asf(d01.w & 0xffff0000u)
                    + w10 * asf(d10.w & 0xffff0000u) + w11 * asf(d11.w & 0xffff0000u);
        }
    }

    short8 o;
    #pragma unroll
    for (int j = 0; j < 8; ++j) o[j] = (short)f2bf(acc[j]);
    *(short8*)(out_pre + (size_t)iq * 256 + sub * 8) = o;
}

// ------------------------------- launcher -------------------------------
extern "C" void kernel_launch(void* const* d_in, const int* in_sizes, int n_in,
                              void* d_out, int out_size, void* d_ws, size_t ws_size,
                              hipStream_t stream)
{
    const float* query  = (const float*)d_in[0];
    const float* refp   = (const float*)d_in[1];
    const float* value  = (const float*)d_in[2];
    const float* w_off  = (const float*)d_in[3];
    const float* b_off  = (const float*)d_in[4];
    const float* w_attn = (const float*)d_in[5];
    const float* b_attn = (const float*)d_in[6];
    const float* w_v    = (const float*)d_in[7];
    const float* b_v    = (const float*)d_in[8];
    const float* w_o    = (const float*)d_in[9];
    const float* b_o    = (const float*)d_in[10];
    (void)d_in[11]; (void)d_in[12];  // shapes/starts fixed by problem, hardcoded

    float* out = (float*)d_out;

    // workspace layout (bytes, 16B-aligned)
    char* ws = (char*)d_ws;
    unsigned short* v_proj  = (unsigned short*)ws;                    // 34,816,000
    float*          offattn = (float*)(ws + 34816000);                // 12,288,000
    unsigned short* outpre  = (unsigned short*)(ws + 47104000);       //  4,096,000
    unsigned short* wv_f    = (unsigned short*)(ws + 51200000);       //    131,072
    unsigned short* woa_f   = (unsigned short*)(ws + 51331072);       //    196,608
    unsigned short* wo_f    = (unsigned short*)(ws + 51527680);       //    131,072  (end 51,658,752)

    dim3 blk(256);

    hipLaunchKernelGGL(wtransform, dim3(112), blk, 0, stream,
                       w_v, w_off, w_attn, w_o, wv_f, woa_f, wo_f);
    // v_proj = value @ w_v + b_v  (fp32 A fused-cast, bf16 out)  [68000 x 256]
    // 532 M-tiles, grid-stride x266 -> 2 tiles/block, 532 blocks ~= 2/CU
    hipLaunchKernelGGL((mfma_gemm_lds<false, true>), dim3(266, 2), blk, 0, stream,
                       value, wv_f, b_v, nullptr, 1 << 30, v_proj, MV);
    // offattn = query @ [w_off | w_attn] + bias  (fp32 out)  [8000 x 384]
    hipLaunchKernelGGL((mfma_gemm_lds<false, false>), dim3(63, 3), blk, 0, stream,
                       query, woa_f, b_off, b_attn, 256, offattn, NQ);
    // sampling + softmax + head weighting -> out_pre bf16  [8000 x 256]
    hipLaunchKernelGGL(ms_sample, dim3(1000), blk, 0, stream,
                       v_proj, offattn, refp, outpre);
    // out = out_pre @ w_o + b_o  [8000 x 256] fp32
    hipLaunchKernelGGL((mfma_gemm_lds<true, false>), dim3(63, 2), blk, 0, stream,
                       outpre, wo_f, b_o, nullptr, 1 << 30, out, NQ);
}

// Round 7
// 214.307 us; speedup vs baseline: 1.2105x; 1.0819x over previous
//
#include <hip/hip_runtime.h>
#include <hip/hip_bf16.h>
#include <math.h>

// Problem constants (fixed by setup_inputs)
#define BS     8
#define LQ     1000
#define DMODEL 256
#define NH     8
#define NLV    4
#define NPT    4
#define LEN_V  8500          // 80*80+40*40+20*20+10*10
#define NQ     (BS*LQ)       // 8000
#define MV     (BS*LEN_V)    // 68000
#define KS     8             // K=256 / 32 per mfma step

typedef __attribute__((ext_vector_type(8))) short short8;     // 8 bf16 (4 VGPRs)
typedef __attribute__((ext_vector_type(4))) float floatx4;

static __device__ __forceinline__ unsigned short f2bf(float f) {
    __hip_bfloat16 h = __float2bfloat16(f);   // RNE
    return __builtin_bit_cast(unsigned short, h);
}
static __device__ __forceinline__ float asf(unsigned int u) {
    return __builtin_bit_cast(float, u);
}

// ---------------------------------------------------------------------------
// Double-buffered, XOR-swizzled MFMA GEMM. C[M,N] = A[M,256] @ B[256,N] + bias.
//   - BM=64 row tiles; LDS = 2 x 32 KB (64 KB total) -> 2 blocks/CU.
//   - Swizzle: 16B group g of row r stored at g ^ (r&7) -> conflict-free
//     ds_read_b128 / ds_write with no pad.
//   - Pipeline: prefetch tile t+1 into registers right after the barrier,
//     K-loop + epilogue of tile t overlap the loads; ONE barrier per tile.
//   - 4 waves, each owns a 32-col quarter (64r x 32c): Bf[2][8]=64 VGPR,
//     acc[4][2]=32, hold[16]=64 -> ~200 VGPR live, fits 256 cap (2 waves/EU).
//   - B pre-shuffled fragment layout: chunk (u=n/16, s=k/32):
//       elem(lane l, j) = B[s*32 + (l>>4)*8 + j][u*16 + (l&15)]
// ---------------------------------------------------------------------------
template <bool A_BF16, bool OUT_BF16>
__global__ __launch_bounds__(256, 2) void mfma_gemm_db(
    const void* __restrict__ Aptr, const unsigned short* __restrict__ Bfrag,
    const float* __restrict__ bias1, const float* __restrict__ bias2, int nsplit,
    void* __restrict__ Cptr, int M)
{
    __shared__ unsigned short As[2][16384];   // 2 x 32,768 B

    const int tid = threadIdx.x;
    const int l   = tid & 63;
    const int w   = tid >> 6;          // wave = column quarter (0..3)
    const int bn  = blockIdx.y;
    const int lm  = l & 15;
    const int lk  = l >> 4;
    const int x7  = lm & 7;
    const int N   = (int)gridDim.y * 128;
    const int n_mtiles = (M + 63) >> 6;

    // ---- B fragments for this wave's 32-col strip (loop-invariant) ----
    short8 Bf[2][KS];
    const int u0 = bn * 8 + w * 2;
    #pragma unroll
    for (int j = 0; j < 2; ++j)
        #pragma unroll
        for (int s = 0; s < KS; ++s)
            Bf[j][s] = *(const short8*)(Bfrag + ((size_t)((u0 + j) * KS + s) * 64 + l) * 8);

    const unsigned short* Ab = (const unsigned short*)Aptr;
    const float*          Af = (const float*)Aptr;

    float4 holdf[16];
    short8 holdb[8];

    auto prefetch = [&](int tile) {
        if (A_BF16) {
            #pragma unroll
            for (int j = 0; j < 8; ++j) {            // 8*256 = 2048 short8 = 64x256
                const int vi  = j * 256 + tid;
                const int row = vi >> 5, g = vi & 31;
                int grow = tile * 64 + row; grow = grow < M ? grow : M - 1;
                holdb[j] = *(const short8*)(Ab + (size_t)grow * 256 + g * 8);
            }
        } else {
            #pragma unroll
            for (int j = 0; j < 16; ++j) {           // 16*256 = 4096 float4 = 64x256
                const int vi  = j * 256 + tid;
                const int row = vi >> 6, c4 = vi & 63;
                int grow = tile * 64 + row; grow = grow < M ? grow : M - 1;
                holdf[j] = *(const float4*)(Af + (size_t)grow * 256 + c4 * 4);
            }
        }
    };

    int bm  = blockIdx.x;
    int buf = 0;
    prefetch(bm);

    while (bm < n_mtiles) {
        const int bm_next = bm + (int)gridDim.x;

        // ---- commit held tile -> LDS[buf] (swizzled) ----
        if (A_BF16) {
            #pragma unroll
            for (int j = 0; j < 8; ++j) {
                const int vi  = j * 256 + tid;
                const int row = vi >> 5, g = vi & 31;
                const int phys = g ^ (row & 7);
                *(short8*)(&As[buf][row * 256 + phys * 8]) = holdb[j];
            }
        } else {
            #pragma unroll
            for (int j = 0; j < 16; ++j) {
                const int vi  = j * 256 + tid;
                const int row = vi >> 6, c4 = vi & 63;
                const int g = c4 >> 1, half = c4 & 1;
                const int phys = g ^ (row & 7);
                float4 f = holdf[j];
                ushort4 h;
                h.x = f2bf(f.x); h.y = f2bf(f.y); h.z = f2bf(f.z); h.w = f2bf(f.w);
                *(ushort4*)(&As[buf][row * 256 + phys * 8 + half * 4]) = h;
            }
        }
        __syncthreads();

        // ---- issue next tile's global loads; K-loop below hides them ----
        if (bm_next < n_mtiles) prefetch(bm_next);

        // ---- K-loop: pure LDS + MFMA ----
        floatx4 acc[4][2];
        #pragma unroll
        for (int i = 0; i < 4; ++i)
            #pragma unroll
            for (int j = 0; j < 2; ++j)
                #pragma unroll
                for (int r = 0; r < 4; ++r) acc[i][j][r] = 0.f;

        #pragma unroll
        for (int s = 0; s < KS; ++s) {
            short8 afr[4];
            #pragma unroll
            for (int i = 0; i < 4; ++i)
                afr[i] = *(const short8*)(
                    &As[buf][(i * 16 + lm) * 256 + (((s * 4 + lk) ^ x7)) * 8]);
            #pragma unroll
            for (int i = 0; i < 4; ++i)
                #pragma unroll
                for (int j = 0; j < 2; ++j)
                    acc[i][j] = __builtin_amdgcn_mfma_f32_16x16x32_bf16(
                                    afr[i], Bf[j][s], acc[i][j], 0, 0, 0);
        }

        // ---- epilogue: bias + store (C layout: col=lane&15, row=lk*4+r) ----
        #pragma unroll
        for (int j = 0; j < 2; ++j) {
            const int col = bn * 128 + w * 32 + j * 16 + lm;
            const float bv = (bias2 != nullptr && col >= nsplit) ? bias2[col - nsplit]
                                                                 : bias1[col];
            #pragma unroll
            for (int i = 0; i < 4; ++i) {
                const int rbase = bm * 64 + i * 16 + lk * 4;
                #pragma unroll
                for (int r = 0; r < 4; ++r) {
                    const int row = rbase + r;
                    if (row < M) {
                        const float v = acc[i][j][r] + bv;
                        if (OUT_BF16)
                            ((unsigned short*)Cptr)[(size_t)row * N + col] = f2bf(v);
                        else
                            ((float*)Cptr)[(size_t)row * N + col] = v;
                    }
                }
            }
        }

        buf ^= 1;
        bm = bm_next;
    }
}

// ------------------- weights -> bf16 fragment layout (one-shot) -------------------
__global__ __launch_bounds__(256) void wtransform(
    const float* __restrict__ w_v, const float* __restrict__ w_off,
    const float* __restrict__ w_attn, const float* __restrict__ w_o,
    unsigned short* __restrict__ wv_f, unsigned short* __restrict__ woa_f,
    unsigned short* __restrict__ wo_f)
{
    const int gid = blockIdx.x * 256 + threadIdx.x;   // 28672 total, grid exact
    int chunk, mode;
    if (gid < 8192)               { chunk = gid;         mode = 0; }
    else if (gid < 8192 + 12288)  { chunk = gid - 8192;  mode = 1; }
    else                          { chunk = gid - 20480; mode = 2; }
    const int l = chunk & 63, s = (chunk >> 6) & 7, u = chunk >> 9;
    short8 o;
    #pragma unroll
    for (int j = 0; j < 8; ++j) {
        const int k = s * 32 + (l >> 4) * 8 + j;
        const int n = u * 16 + (l & 15);
        float v;
        if (mode == 0)      v = w_v[k * 256 + n];
        else if (mode == 1) v = (n < 256) ? w_off[k * 256 + n] : w_attn[k * 128 + (n - 256)];
        else                v = w_o[k * 256 + n];
        o[j] = (short)f2bf(v);
    }
    unsigned short* dp = (mode == 0 ? wv_f : mode == 1 ? woa_f : wo_f)
                         + ((size_t)(u * 8 + s) * 64 + l) * 8;
    *(short8*)dp = o;
}

// ---------------- softmax + bilinear sampling + head weighting ----------------
// 8 queries per block, 1000 blocks. thread = (q8 = tid>>5, h = (tid>>2)&7,
// oct = tid&3). Each thread accumulates 8 channels (16-B short8 gathers).
__global__ __launch_bounds__(256) void ms_sample(
    const unsigned short* __restrict__ v,    // [BS,8500,256] bf16
    const float* __restrict__ offattn,       // [NQ,384]: offs[0:256) | logits[256:384)
    const float* __restrict__ refp,          // [NQ,4,2]
    unsigned short* __restrict__ out_pre)    // [NQ,256] bf16
{
    __shared__ float offx_s[8][16][8];   // [q][lvl*4+p][h] — h on distinct banks
    __shared__ float offy_s[8][16][8];
    __shared__ float atw_s [8][16][8];
    __shared__ float ref_s [8][8];

    const int tid = threadIdx.x;
    const int iq0 = blockIdx.x * 8;

    if (tid < 64) {
        const int q = tid >> 3, h = tid & 7;
        const float* rowp = offattn + (size_t)(iq0 + q) * 384;
        float lg[16];
        float m = -1e30f;
        #pragma unroll
        for (int i = 0; i < 16; ++i) { lg[i] = rowp[256 + h * 16 + i]; m = fmaxf(m, lg[i]); }
        float s = 0.f;
        #pragma unroll
        for (int i = 0; i < 16; ++i) { lg[i] = __expf(lg[i] - m); s += lg[i]; }
        const float inv = 1.f / s;
        #pragma unroll
        for (int i = 0; i < 16; ++i) atw_s[q][i][h] = lg[i] * inv;
        #pragma unroll
        for (int i = 0; i < 16; ++i) {
            offx_s[q][i][h] = rowp[(h * 16 + i) * 2 + 0];
            offy_s[q][i][h] = rowp[(h * 16 + i) * 2 + 1];
        }
        if (h == 0) {
            #pragma unroll
            for (int i = 0; i < 8; ++i) ref_s[q][i] = refp[(size_t)(iq0 + q) * 8 + i];
        }
    }
    __syncthreads();

    const int q8  = tid >> 5;
    const int sub = tid & 31;
    const int h   = sub >> 2;
    const int oct = sub & 3;
    const int iq  = iq0 + q8;
    const int b   = iq / LQ;             // 8 | LQ, whole block same batch

    float acc[8] = {0.f, 0.f, 0.f, 0.f, 0.f, 0.f, 0.f, 0.f};
    const unsigned short* vb = v + (size_t)b * LEN_V * 256 + h * 32 + oct * 8;
    const int Hs[4] = {80, 40, 20, 10};
    const int st[4] = {0, 6400, 8000, 8400};

    #pragma unroll
    for (int lvl = 0; lvl < NLV; ++lvl) {
        const int W = Hs[lvl];
        const float bx = ref_s[q8][lvl * 2 + 0] * (float)W - 0.5f;
        const float by = ref_s[q8][lvl * 2 + 1] * (float)W - 0.5f;
        const unsigned short* vl = vb + (size_t)st[lvl] * 256;
        #pragma unroll
        for (int p = 0; p < NPT; ++p) {
            const int lp = lvl * 4 + p;
            const float x  = bx + offx_s[q8][lp][h];
            const float y  = by + offy_s[q8][lp][h];
            const float at = atw_s[q8][lp][h];
            const float x0f = floorf(x), y0f = floorf(y);
            const float fx = x - x0f, fy = y - y0f;
            const int x0 = (int)x0f, y0 = (int)y0f;
            const int x1 = x0 + 1,   y1 = y0 + 1;
            const int cx0 = min(max(x0, 0), W - 1);
            const int cx1 = min(max(x1, 0), W - 1);
            const int cy0 = min(max(y0, 0), W - 1);
            const int cy1 = min(max(y1, 0), W - 1);
            const float vx0 = (x0 >= 0 && x0 < W) ? 1.f : 0.f;
            const float vx1 = (x1 >= 0 && x1 < W) ? 1.f : 0.f;
            const float vy0 = (y0 >= 0 && y0 < W) ? 1.f : 0.f;
            const float vy1 = (y1 >= 0 && y1 < W) ? 1.f : 0.f;
            const float w00 = at * (1.f - fx) * (1.f - fy) * vx0 * vy0;
            const float w01 = at * fx * (1.f - fy) * vx1 * vy0;
            const float w10 = at * (1.f - fx) * fy * vx0 * vy1;
            const float w11 = at * fx * fy * vx1 * vy1;
            const unsigned short* r0 = vl + (size_t)(cy0 * W) * 256;
            const unsigned short* r1 = vl + (size_t)(cy1 * W) * 256;
            const uint4 d00 = *(const uint4*)(r0 + (size_t)cx0 * 256);
            const uint4 d01 = *(const uint4*)(r0 + (size_t)cx1 * 256);
            const uint4 d10 = *(const uint4*)(r1 + (size_t)cx0 * 256);
            const uint4 d11 = *(const uint4*)(r1 + (size_t)cx1 * 256);
            acc[0] += w00 * asf(d00.x << 16) + w01 * asf(d01.x << 16)
                    + w10 * asf(d10.x << 16) + w11 * asf(d11.x << 16);
            acc[1] += w00 * asf(d00.x & 0xffff0000u) + w01 * asf(d01.x & 0xffff0000u)
                    + w10 * asf(d10.x & 0xffff0000u) + w11 * asf(d11.x & 0xffff0000u);
            acc[2] += w00 * asf(d00.y << 16) + w01 * asf(d01.y << 16)
                    + w10 * asf(d10.y << 16) + w11 * asf(d11.y << 16);
            acc[3] += w00 * asf(d00.y & 0xffff0000u) + w01 * asf(d01.y & 0xffff0000u)
                    + w10 * asf(d10.y & 0xffff0000u) + w11 * asf(d11.y & 0xffff0000u);
            acc[4] += w00 * asf(d00.z << 16) + w01 * asf(d01.z << 16)
                    + w10 * asf(d10.z << 16) + w11 * asf(d11.z << 16);
            acc[5] += w00 * asf(d00.z & 0xffff0000u) + w01 * asf(d01.z & 0xffff0000u)
                    + w10 * asf(d10.z & 0xffff0000u) + w11 * asf(d11.z & 0xffff0000u);
            acc[6] += w00 * asf(d00.w << 16) + w01 * asf(d01.w << 16)
                    + w10 * asf(d10.w << 16) + w11 * asf(d11.w << 16);
            acc[7] += w00 * asf(d00.w & 0xffff0000u) + w01 * asf(d01.w & 0xffff0000u)
                    + w10 * asf(d10.w & 0xffff0000u) + w11 * asf(d11.w & 0xffff0000u);
        }
    }

    short8 o;
    #pragma unroll
    for (int j = 0; j < 8; ++j) o[j] = (short)f2bf(acc[j]);
    *(short8*)(out_pre + (size_t)iq * 256 + sub * 8) = o;
}

// ------------------------------- launcher -------------------------------
extern "C" void kernel_launch(void* const* d_in, const int* in_sizes, int n_in,
                              void* d_out, int out_size, void* d_ws, size_t ws_size,
                              hipStream_t stream)
{
    const float* query  = (const float*)d_in[0];
    const float* refp   = (const float*)d_in[1];
    const float* value  = (const float*)d_in[2];
    const float* w_off  = (const float*)d_in[3];
    const float* b_off  = (const float*)d_in[4];
    const float* w_attn = (const float*)d_in[5];
    const float* b_attn = (const float*)d_in[6];
    const float* w_v    = (const float*)d_in[7];
    const float* b_v    = (const float*)d_in[8];
    const float* w_o    = (const float*)d_in[9];
    const float* b_o    = (const float*)d_in[10];
    (void)d_in[11]; (void)d_in[12];  // shapes/starts fixed by problem, hardcoded

    float* out = (float*)d_out;

    // workspace layout (bytes, 16B-aligned)
    char* ws = (char*)d_ws;
    unsigned short* v_proj  = (unsigned short*)ws;                    // 34,816,000
    float*          offattn = (float*)(ws + 34816000);                // 12,288,000
    unsigned short* outpre  = (unsigned short*)(ws + 47104000);       //  4,096,000
    unsigned short* wv_f    = (unsigned short*)(ws + 51200000);       //    131,072
    unsigned short* woa_f   = (unsigned short*)(ws + 51331072);       //    196,608
    unsigned short* wo_f    = (unsigned short*)(ws + 51527680);       //    131,072  (end 51,658,752)

    dim3 blk(256);

    hipLaunchKernelGGL(wtransform, dim3(112), blk, 0, stream,
                       w_v, w_off, w_attn, w_o, wv_f, woa_f, wo_f);
    // v_proj = value @ w_v + b_v  (fp32 A fused-cast, bf16 out)  [68000 x 256]
    // 1063 64-row tiles, 256 blocks/strip x 2 strips = 512 blocks (2/CU), ~4 tiles each
    hipLaunchKernelGGL((mfma_gemm_db<false, true>), dim3(256, 2), blk, 0, stream,
                       value, wv_f, b_v, nullptr, 1 << 30, v_proj, MV);
    // offattn = query @ [w_off | w_attn] + bias  (fp32 out)  [8000 x 384]
    hipLaunchKernelGGL((mfma_gemm_db<false, false>), dim3(63, 3), blk, 0, stream,
                       query, woa_f, b_off, b_attn, 256, offattn, NQ);
    // sampling + softmax + head weighting -> out_pre bf16  [8000 x 256]
    hipLaunchKernelGGL(ms_sample, dim3(1000), blk, 0, stream,
                       v_proj, offattn, refp, outpre);
    // out = out_pre @ w_o + b_o  [8000 x 256] fp32
    hipLaunchKernelGGL((mfma_gemm_db<true, false>), dim3(63, 2), blk, 0, stream,
                       outpre, wo_f, b_o, nullptr, 1 << 30, out, NQ);
}

// Round 8
// 213.238 us; speedup vs baseline: 1.2166x; 1.0050x over previous
//
#include <hip/hip_runtime.h>
#include <hip/hip_bf16.h>
#include <math.h>

// Problem constants (fixed by setup_inputs)
#define BS     8
#define LQ     1000
#define DMODEL 256
#define NH     8
#define NLV    4
#define NPT    4
#define LEN_V  8500          // 80*80+40*40+20*20+10*10
#define NQ     (BS*LQ)       // 8000
#define MV     (BS*LEN_V)    // 68000
#define KS     8             // K=256 / 32 per mfma step

typedef __attribute__((ext_vector_type(8))) short short8;     // 8 bf16 (4 VGPRs)
typedef __attribute__((ext_vector_type(4))) float floatx4;

static __device__ __forceinline__ unsigned short f2bf(float f) {
    __hip_bfloat16 h = __float2bfloat16(f);   // RNE
    return __builtin_bit_cast(unsigned short, h);
}
static __device__ __forceinline__ float asf(unsigned int u) {
    return __builtin_bit_cast(float, u);
}

// async global->LDS DMA, 16B per lane; LDS dest = wave-uniform base + lane*16
static __device__ __forceinline__ void dma16(const unsigned short* g, unsigned short* lds) {
    __builtin_amdgcn_global_load_lds(
        (const __attribute__((address_space(1))) unsigned int*)g,
        (__attribute__((address_space(3))) unsigned int*)lds,
        16, 0, 0);
}

// ---------------------------------------------------------------------------
// DMA double-buffered MFMA GEMM. C[M,N] = A[M,256] @ B[256,N] + bias.
//   A: bf16 row-major. Staged via global_load_lds into 2 x 32KB LDS buffers.
//   Swizzle: logical 16B chunk c of row r lives at LDS pos c ^ (r&7); since the
//   DMA dest is fixed (base+lane*16), the SOURCE address is inverse-permuted.
//   Pipeline: wait DMA(t) [waitcnt+barrier], issue DMA(t+1) into other buffer,
//   then K-loop(t) overlaps DMA(t+1). One barrier per tile. No hold VGPRs.
//   4 waves, wave = 64r x 32c quarter; Bf[2][8]=64 VGPR, acc 32.
// ---------------------------------------------------------------------------
template <bool OUT_BF16>
__global__ __launch_bounds__(256, 2) void mfma_gemm_dma(
    const unsigned short* __restrict__ Ab, const unsigned short* __restrict__ Bfrag,
    const float* __restrict__ bias1, const float* __restrict__ bias2, int nsplit,
    void* __restrict__ Cptr, int M)
{
    __shared__ unsigned short As[2][16384];   // 2 x 32,768 B

    const int tid = threadIdx.x;
    const int l   = tid & 63;
    const int w   = tid >> 6;          // wave = column quarter (0..3)
    const int bn  = blockIdx.y;
    const int lm  = l & 15;
    const int lk  = l >> 4;
    const int x7  = lm & 7;
    const int N   = (int)gridDim.y * 128;
    const int n_mtiles = (M + 63) >> 6;

    // ---- B fragments for this wave's 32-col strip (loop-invariant) ----
    short8 Bf[2][KS];
    const int u0 = bn * 8 + w * 2;
    #pragma unroll
    for (int j = 0; j < 2; ++j)
        #pragma unroll
        for (int s = 0; s < KS; ++s)
            Bf[j][s] = *(const short8*)(Bfrag + ((size_t)((u0 + j) * KS + s) * 64 + l) * 8);

    auto dma_tile = [&](int tile, int buf) {
        #pragma unroll
        for (int j = 0; j < 8; ++j) {                 // 8 * 256 lanes * 16B = 32KB
            const int slot = j * 256 + tid;           // chunk slot in [64][32]
            const int row  = slot >> 5;
            const int gp   = slot & 31;               // physical chunk pos
            const int gc   = gp ^ (row & 7);          // logical chunk fetched here
            int grow = tile * 64 + row; grow = grow < M ? grow : M - 1;
            dma16(Ab + (size_t)grow * 256 + gc * 8,
                  &As[buf][(j * 256 + w * 64) * 8]);  // uniform base; HW adds lane*16
        }
    };

    int bm  = blockIdx.x;
    int buf = 0;
    if (bm < n_mtiles) dma_tile(bm, 0);

    while (bm < n_mtiles) {
        const int bm_next = bm + (int)gridDim.x;

        __builtin_amdgcn_s_waitcnt(0);   // DMA(bm) complete (drains all counters)
        __syncthreads();
        if (bm_next < n_mtiles) dma_tile(bm_next, buf ^ 1);  // flies during K-loop

        floatx4 acc[4][2];
        #pragma unroll
        for (int i = 0; i < 4; ++i)
            #pragma unroll
            for (int j = 0; j < 2; ++j)
                #pragma unroll
                for (int r = 0; r < 4; ++r) acc[i][j][r] = 0.f;

        #pragma unroll
        for (int s = 0; s < KS; ++s) {
            short8 afr[4];
            #pragma unroll
            for (int i = 0; i < 4; ++i)
                afr[i] = *(const short8*)(
                    &As[buf][(i * 16 + lm) * 256 + (((s * 4 + lk) ^ x7)) * 8]);
            #pragma unroll
            for (int i = 0; i < 4; ++i)
                #pragma unroll
                for (int j = 0; j < 2; ++j)
                    acc[i][j] = __builtin_amdgcn_mfma_f32_16x16x32_bf16(
                                    afr[i], Bf[j][s], acc[i][j], 0, 0, 0);
        }

        #pragma unroll
        for (int j = 0; j < 2; ++j) {
            const int col = bn * 128 + w * 32 + j * 16 + lm;
            const float bv = (bias2 != nullptr && col >= nsplit) ? bias2[col - nsplit]
                                                                 : bias1[col];
            #pragma unroll
            for (int i = 0; i < 4; ++i) {
                const int rbase = bm * 64 + i * 16 + lk * 4;
                #pragma unroll
                for (int r = 0; r < 4; ++r) {
                    const int row = rbase + r;
                    if (row < M) {
                        const float v = acc[i][j][r] + bv;
                        if (OUT_BF16)
                            ((unsigned short*)Cptr)[(size_t)row * N + col] = f2bf(v);
                        else
                            ((float*)Cptr)[(size_t)row * N + col] = v;
                    }
                }
            }
        }

        buf ^= 1;
        bm = bm_next;
    }
}

// ------------------- weights -> bf16 fragment layout (one-shot) -------------------
__global__ __launch_bounds__(256) void wtransform(
    const float* __restrict__ w_v, const float* __restrict__ w_off,
    const float* __restrict__ w_attn, const float* __restrict__ w_o,
    unsigned short* __restrict__ wv_f, unsigned short* __restrict__ woa_f,
    unsigned short* __restrict__ wo_f)
{
    const int gid = blockIdx.x * 256 + threadIdx.x;   // 28672 total, grid exact
    int chunk, mode;
    if (gid < 8192)               { chunk = gid;         mode = 0; }
    else if (gid < 8192 + 12288)  { chunk = gid - 8192;  mode = 1; }
    else                          { chunk = gid - 20480; mode = 2; }
    const int l = chunk & 63, s = (chunk >> 6) & 7, u = chunk >> 9;
    short8 o;
    #pragma unroll
    for (int j = 0; j < 8; ++j) {
        const int k = s * 32 + (l >> 4) * 8 + j;
        const int n = u * 16 + (l & 15);
        float v;
        if (mode == 0)      v = w_v[k * 256 + n];
        else if (mode == 1) v = (n < 256) ? w_off[k * 256 + n] : w_attn[k * 128 + (n - 256)];
        else                v = w_o[k * 256 + n];
        o[j] = (short)f2bf(v);
    }
    unsigned short* dp = (mode == 0 ? wv_f : mode == 1 ? woa_f : wo_f)
                         + ((size_t)(u * 8 + s) * 64 + l) * 8;
    *(short8*)dp = o;
}

// --------------- fp32 -> bf16 cast: value (17.408M) then query (2.048M) ---------------
__global__ __launch_bounds__(256) void cast2_bf16(const float* __restrict__ value,
                                                  const float* __restrict__ query,
                                                  unsigned short* __restrict__ out)
{
    const int i = blockIdx.x * 256 + threadIdx.x;     // 4,864,000 float4 total, exact
    const float4 v = (i < 4352000) ? ((const float4*)value)[i]
                                   : ((const float4*)query)[i - 4352000];
    ushort4 o;
    o.x = f2bf(v.x); o.y = f2bf(v.y); o.z = f2bf(v.z); o.w = f2bf(v.w);
    ((ushort4*)out)[i] = o;
}

// ---- softmax + bilinear sampling + head weighting + FUSED out-projection ----
// 8 queries/block, 1000 blocks, XCD-swizzled so each batch stays on one XCD.
// Phase 1: thread=(q8,h,oct) accumulates 8 channels -> P[8][256] bf16 in LDS.
// Phase 2: P @ w_o (16x16x32 MFMA, rows 8..15 zero) + b_o -> d_out fp32.
__global__ __launch_bounds__(256) void ms_sample_fused(
    const unsigned short* __restrict__ v,    // [BS,8500,256] bf16
    const float* __restrict__ offattn,       // [NQ,384]: offs[0:256) | logits[256:384)
    const float* __restrict__ refp,          // [NQ,4,2]
    const unsigned short* __restrict__ wo_f, // w_o fragment layout
    const float* __restrict__ b_o,           // [256]
    float* __restrict__ out)                 // [NQ,256] fp32
{
    __shared__ float offx_s[8][16][8];
    __shared__ float offy_s[8][16][8];
    __shared__ float atw_s [8][16][8];
    __shared__ float ref_s [8][8];
    __shared__ unsigned short P[8][256];     // sampled features, bf16

    const int tid = threadIdx.x;
    const int bswz = blockIdx.x & 7;                       // batch -> XCD
    const int iq0  = bswz * 1000 + (blockIdx.x >> 3) * 8;  // 8 queries, same batch

    if (tid < 64) {
        const int q = tid >> 3, h = tid & 7;
        const float* rowp = offattn + (size_t)(iq0 + q) * 384;
        float lg[16];
        float m = -1e30f;
        #pragma unroll
        for (int i = 0; i < 16; ++i) { lg[i] = rowp[256 + h * 16 + i]; m = fmaxf(m, lg[i]); }
        float s = 0.f;
        #pragma unroll
        for (int i = 0; i < 16; ++i) { lg[i] = __expf(lg[i] - m); s += lg[i]; }
        const float inv = 1.f / s;
        #pragma unroll
        for (int i = 0; i < 16; ++i) atw_s[q][i][h] = lg[i] * inv;
        #pragma unroll
        for (int i = 0; i < 16; ++i) {
            offx_s[q][i][h] = rowp[(h * 16 + i) * 2 + 0];
            offy_s[q][i][h] = rowp[(h * 16 + i) * 2 + 1];
        }
        if (h == 0) {
            #pragma unroll
            for (int i = 0; i < 8; ++i) ref_s[q][i] = refp[(size_t)(iq0 + q) * 8 + i];
        }
    }
    __syncthreads();

    const int q8  = tid >> 5;
    const int sub = tid & 31;
    const int h   = sub >> 2;
    const int oct = sub & 3;

    float acc[8] = {0.f, 0.f, 0.f, 0.f, 0.f, 0.f, 0.f, 0.f};
    const unsigned short* vb = v + (size_t)bswz * LEN_V * 256 + h * 32 + oct * 8;
    const int Hs[4] = {80, 40, 20, 10};
    const int st[4] = {0, 6400, 8000, 8400};

    #pragma unroll
    for (int lvl = 0; lvl < NLV; ++lvl) {
        const int W = Hs[lvl];
        const float bx = ref_s[q8][lvl * 2 + 0] * (float)W - 0.5f;
        const float by = ref_s[q8][lvl * 2 + 1] * (float)W - 0.5f;
        const unsigned short* vl = vb + (size_t)st[lvl] * 256;
        #pragma unroll
        for (int p = 0; p < NPT; ++p) {
            const int lp = lvl * 4 + p;
            const float x  = bx + offx_s[q8][lp][h];
            const float y  = by + offy_s[q8][lp][h];
            const float at = atw_s[q8][lp][h];
            const float x0f = floorf(x), y0f = floorf(y);
            const float fx = x - x0f, fy = y - y0f;
            const int x0 = (int)x0f, y0 = (int)y0f;
            const int x1 = x0 + 1,   y1 = y0 + 1;
            const int cx0 = min(max(x0, 0), W - 1);
            const int cx1 = min(max(x1, 0), W - 1);
            const int cy0 = min(max(y0, 0), W - 1);
            const int cy1 = min(max(y1, 0), W - 1);
            const float vx0 = (x0 >= 0 && x0 < W) ? 1.f : 0.f;
            const float vx1 = (x1 >= 0 && x1 < W) ? 1.f : 0.f;
            const float vy0 = (y0 >= 0 && y0 < W) ? 1.f : 0.f;
            const float vy1 = (y1 >= 0 && y1 < W) ? 1.f : 0.f;
            const float w00 = at * (1.f - fx) * (1.f - fy) * vx0 * vy0;
            const float w01 = at * fx * (1.f - fy) * vx1 * vy0;
            const float w10 = at * (1.f - fx) * fy * vx0 * vy1;
            const float w11 = at * fx * fy * vx1 * vy1;
            const unsigned short* r0 = vl + (size_t)(cy0 * W) * 256;
            const unsigned short* r1 = vl + (size_t)(cy1 * W) * 256;
            const uint4 d00 = *(const uint4*)(r0 + (size_t)cx0 * 256);
            const uint4 d01 = *(const uint4*)(r0 + (size_t)cx1 * 256);
            const uint4 d10 = *(const uint4*)(r1 + (size_t)cx0 * 256);
            const uint4 d11 = *(const uint4*)(r1 + (size_t)cx1 * 256);
            acc[0] += w00 * asf(d00.x << 16) + w01 * asf(d01.x << 16)
                    + w10 * asf(d10.x << 16) + w11 * asf(d11.x << 16);
            acc[1] += w00 * asf(d00.x & 0xffff0000u) + w01 * asf(d01.x & 0xffff0000u)
                    + w10 * asf(d10.x & 0xffff0000u) + w11 * asf(d11.x & 0xffff0000u);
            acc[2] += w00 * asf(d00.y << 16) + w01 * asf(d01.y << 16)
                    + w10 * asf(d10.y << 16) + w11 * asf(d11.y << 16);
            acc[3] += w00 * asf(d00.y & 0xffff0000u) + w01 * asf(d01.y & 0xffff0000u)
                    + w10 * asf(d10.y & 0xffff0000u) + w11 * asf(d11.y & 0xffff0000u);
            acc[4] += w00 * asf(d00.z << 16) + w01 * asf(d01.z << 16)
                    + w10 * asf(d10.z << 16) + w11 * asf(d11.z << 16);
            acc[5] += w00 * asf(d00.z & 0xffff0000u) + w01 * asf(d01.z & 0xffff0000u)
                    + w10 * asf(d10.z & 0xffff0000u) + w11 * asf(d11.z & 0xffff0000u);
            acc[6] += w00 * asf(d00.w << 16) + w01 * asf(d01.w << 16)
                    + w10 * asf(d10.w << 16) + w11 * asf(d11.w << 16);
            acc[7] += w00 * asf(d00.w & 0xffff0000u) + w01 * asf(d01.w & 0xffff0000u)
                    + w10 * asf(d10.w & 0xffff0000u) + w11 * asf(d11.w & 0xffff0000u);
        }
    }

    {
        short8 o;
        #pragma unroll
        for (int j = 0; j < 8; ++j) o[j] = (short)f2bf(acc[j]);
        *(short8*)(&P[q8][sub * 8]) = o;
    }
    __syncthreads();

    // ---- fused out-projection: out[iq0+0..7][:] = P @ w_o + b_o ----
    const int l  = tid & 63;
    const int w  = tid >> 6;       // wave -> 64-col strip
    const int lm = l & 15;
    const int lk = l >> 4;

    floatx4 acc2[4];
    #pragma unroll
    for (int jj = 0; jj < 4; ++jj)
        #pragma unroll
        for (int r = 0; r < 4; ++r) acc2[jj][r] = 0.f;

    #pragma unroll
    for (int s = 0; s < KS; ++s) {
        short8 afr;
        if (lm < 8) afr = *(const short8*)(&P[lm][s * 32 + lk * 8]);
        else { short8 z = {0,0,0,0,0,0,0,0}; afr = z; }
        #pragma unroll
        for (int jj = 0; jj < 4; ++jj) {
            const int u = w * 4 + jj;
            short8 bfr = *(const short8*)(wo_f + ((size_t)(u * KS + s) * 64 + l) * 8);
            acc2[jj] = __builtin_amdgcn_mfma_f32_16x16x32_bf16(afr, bfr, acc2[jj], 0, 0, 0);
        }
    }

    if (lk < 2) {
        #pragma unroll
        for (int jj = 0; jj < 4; ++jj) {
            const int col = w * 64 + jj * 16 + lm;
            const float bv = b_o[col];
            #pragma unroll
            for (int r = 0; r < 4; ++r) {
                const int row = lk * 4 + r;        // 0..7 valid
                out[(size_t)(iq0 + row) * 256 + col] = acc2[jj][r] + bv;
            }
        }
    }
}

// ------------------------------- launcher -------------------------------
extern "C" void kernel_launch(void* const* d_in, const int* in_sizes, int n_in,
                              void* d_out, int out_size, void* d_ws, size_t ws_size,
                              hipStream_t stream)
{
    const float* query  = (const float*)d_in[0];
    const float* refp   = (const float*)d_in[1];
    const float* value  = (const float*)d_in[2];
    const float* w_off  = (const float*)d_in[3];
    const float* b_off  = (const float*)d_in[4];
    const float* w_attn = (const float*)d_in[5];
    const float* b_attn = (const float*)d_in[6];
    const float* w_v    = (const float*)d_in[7];
    const float* b_v    = (const float*)d_in[8];
    const float* w_o    = (const float*)d_in[9];
    const float* b_o    = (const float*)d_in[10];
    (void)d_in[11]; (void)d_in[12];  // shapes/starts fixed by problem, hardcoded

    float* out = (float*)d_out;

    // workspace layout (bytes, 16B-aligned; end 86,474,752 == r2's proven size)
    char* ws = (char*)d_ws;
    unsigned short* valq_bf = (unsigned short*)ws;                    // 76000*256*2 = 38,912,000
    unsigned short* v_proj  = (unsigned short*)(ws + 38912000);       // 34,816,000
    float*          offattn = (float*)(ws + 73728000);                // 12,288,000
    unsigned short* wv_f    = (unsigned short*)(ws + 86016000);       //    131,072
    unsigned short* woa_f   = (unsigned short*)(ws + 86147072);       //    196,608
    unsigned short* wo_f    = (unsigned short*)(ws + 86343680);       //    131,072

    dim3 blk(256);

    hipLaunchKernelGGL(wtransform, dim3(112), blk, 0, stream,
                       w_v, w_off, w_attn, w_o, wv_f, woa_f, wo_f);
    // value||query -> bf16 (4,864,000 float4)
    hipLaunchKernelGGL(cast2_bf16, dim3(19000), blk, 0, stream,
                       value, query, valq_bf);
    // v_proj = value_bf @ w_v + b_v  (bf16 out)  [68000 x 256], DMA pipeline
    hipLaunchKernelGGL((mfma_gemm_dma<true>), dim3(532, 2), blk, 0, stream,
                       valq_bf, wv_f, b_v, nullptr, 1 << 30, v_proj, MV);
    // offattn = query_bf @ [w_off | w_attn] + bias  (fp32 out)  [8000 x 384]
    hipLaunchKernelGGL((mfma_gemm_dma<false>), dim3(125, 3), blk, 0, stream,
                       valq_bf + (size_t)MV * 256, woa_f, b_off, b_attn, 256, offattn, NQ);
    // sampling + softmax + fused out-projection -> d_out fp32
    hipLaunchKernelGGL(ms_sample_fused, dim3(1000), blk, 0, stream,
                       v_proj, offattn, refp, wo_f, b_o, out);
}

// Round 9
// 201.766 us; speedup vs baseline: 1.2857x; 1.0569x over previous
//
#include <hip/hip_runtime.h>
#include <hip/hip_bf16.h>
#include <math.h>

// Problem constants (fixed by setup_inputs)
#define BS     8
#define LQ     1000
#define DMODEL 256
#define NH     8
#define NLV    4
#define NPT    4
#define LEN_V  8500          // 80*80+40*40+20*20+10*10
#define NQ     (BS*LQ)       // 8000
#define MV     (BS*LEN_V)    // 68000
#define KS     8             // K=256 / 32 per mfma step

typedef __attribute__((ext_vector_type(8))) short short8;     // 8 bf16 (4 VGPRs)
typedef __attribute__((ext_vector_type(4))) float floatx4;

static __device__ __forceinline__ unsigned short f2bf(float f) {
    __hip_bfloat16 h = __float2bfloat16(f);   // RNE
    return __builtin_bit_cast(unsigned short, h);
}
static __device__ __forceinline__ float asf(unsigned int u) {
    return __builtin_bit_cast(float, u);
}

// async global->LDS DMA, 16B per lane; LDS dest = wave-uniform base + lane*16
static __device__ __forceinline__ void dma16(const unsigned short* g, unsigned short* lds) {
    __builtin_amdgcn_global_load_lds(
        (const __attribute__((address_space(1))) unsigned int*)g,
        (__attribute__((address_space(3))) unsigned int*)lds,
        16, 0, 0);
}

// ---------------------------------------------------------------------------
// DMA double-buffered MFMA GEMM (unchanged from round 8 — proven).
// ---------------------------------------------------------------------------
template <bool OUT_BF16>
__global__ __launch_bounds__(256, 2) void mfma_gemm_dma(
    const unsigned short* __restrict__ Ab, const unsigned short* __restrict__ Bfrag,
    const float* __restrict__ bias1, const float* __restrict__ bias2, int nsplit,
    void* __restrict__ Cptr, int M)
{
    __shared__ unsigned short As[2][16384];   // 2 x 32,768 B

    const int tid = threadIdx.x;
    const int l   = tid & 63;
    const int w   = tid >> 6;          // wave = column quarter (0..3)
    const int bn  = blockIdx.y;
    const int lm  = l & 15;
    const int lk  = l >> 4;
    const int x7  = lm & 7;
    const int N   = (int)gridDim.y * 128;
    const int n_mtiles = (M + 63) >> 6;

    short8 Bf[2][KS];
    const int u0 = bn * 8 + w * 2;
    #pragma unroll
    for (int j = 0; j < 2; ++j)
        #pragma unroll
        for (int s = 0; s < KS; ++s)
            Bf[j][s] = *(const short8*)(Bfrag + ((size_t)((u0 + j) * KS + s) * 64 + l) * 8);

    auto dma_tile = [&](int tile, int buf) {
        #pragma unroll
        for (int j = 0; j < 8; ++j) {                 // 8 * 256 lanes * 16B = 32KB
            const int slot = j * 256 + tid;
            const int row  = slot >> 5;
            const int gp   = slot & 31;               // physical chunk pos
            const int gc   = gp ^ (row & 7);          // logical chunk fetched here
            int grow = tile * 64 + row; grow = grow < M ? grow : M - 1;
            dma16(Ab + (size_t)grow * 256 + gc * 8,
                  &As[buf][(j * 256 + w * 64) * 8]);  // uniform base; HW adds lane*16
        }
    };

    int bm  = blockIdx.x;
    int buf = 0;
    if (bm < n_mtiles) dma_tile(bm, 0);

    while (bm < n_mtiles) {
        const int bm_next = bm + (int)gridDim.x;

        __builtin_amdgcn_s_waitcnt(0);
        __syncthreads();
        if (bm_next < n_mtiles) dma_tile(bm_next, buf ^ 1);  // flies during K-loop

        floatx4 acc[4][2];
        #pragma unroll
        for (int i = 0; i < 4; ++i)
            #pragma unroll
            for (int j = 0; j < 2; ++j)
                #pragma unroll
                for (int r = 0; r < 4; ++r) acc[i][j][r] = 0.f;

        #pragma unroll
        for (int s = 0; s < KS; ++s) {
            short8 afr[4];
            #pragma unroll
            for (int i = 0; i < 4; ++i)
                afr[i] = *(const short8*)(
                    &As[buf][(i * 16 + lm) * 256 + (((s * 4 + lk) ^ x7)) * 8]);
            #pragma unroll
            for (int i = 0; i < 4; ++i)
                #pragma unroll
                for (int j = 0; j < 2; ++j)
                    acc[i][j] = __builtin_amdgcn_mfma_f32_16x16x32_bf16(
                                    afr[i], Bf[j][s], acc[i][j], 0, 0, 0);
        }

        #pragma unroll
        for (int j = 0; j < 2; ++j) {
            const int col = bn * 128 + w * 32 + j * 16 + lm;
            const float bv = (bias2 != nullptr && col >= nsplit) ? bias2[col - nsplit]
                                                                 : bias1[col];
            #pragma unroll
            for (int i = 0; i < 4; ++i) {
                const int rbase = bm * 64 + i * 16 + lk * 4;
                #pragma unroll
                for (int r = 0; r < 4; ++r) {
                    const int row = rbase + r;
                    if (row < M) {
                        const float v = acc[i][j][r] + bv;
                        if (OUT_BF16)
                            ((unsigned short*)Cptr)[(size_t)row * N + col] = f2bf(v);
                        else
                            ((float*)Cptr)[(size_t)row * N + col] = v;
                    }
                }
            }
        }

        buf ^= 1;
        bm = bm_next;
    }
}

// ------------------- weights -> bf16 fragment layout (one-shot) -------------------
__global__ __launch_bounds__(256) void wtransform(
    const float* __restrict__ w_v, const float* __restrict__ w_off,
    const float* __restrict__ w_attn, const float* __restrict__ w_o,
    unsigned short* __restrict__ wv_f, unsigned short* __restrict__ woa_f,
    unsigned short* __restrict__ wo_f)
{
    const int gid = blockIdx.x * 256 + threadIdx.x;   // 28672 total, grid exact
    int chunk, mode;
    if (gid < 8192)               { chunk = gid;         mode = 0; }
    else if (gid < 8192 + 12288)  { chunk = gid - 8192;  mode = 1; }
    else                          { chunk = gid - 20480; mode = 2; }
    const int l = chunk & 63, s = (chunk >> 6) & 7, u = chunk >> 9;
    short8 o;
    #pragma unroll
    for (int j = 0; j < 8; ++j) {
        const int k = s * 32 + (l >> 4) * 8 + j;
        const int n = u * 16 + (l & 15);
        float v;
        if (mode == 0)      v = w_v[k * 256 + n];
        else if (mode == 1) v = (n < 256) ? w_off[k * 256 + n] : w_attn[k * 128 + (n - 256)];
        else                v = w_o[k * 256 + n];
        o[j] = (short)f2bf(v);
    }
    unsigned short* dp = (mode == 0 ? wv_f : mode == 1 ? woa_f : wo_f)
                         + ((size_t)(u * 8 + s) * 64 + l) * 8;
    *(short8*)dp = o;
}

// --------------- fp32 -> bf16 cast: value (17.408M) then query (2.048M) ---------------
__global__ __launch_bounds__(256) void cast2_bf16(const float* __restrict__ value,
                                                  const float* __restrict__ query,
                                                  unsigned short* __restrict__ out)
{
    const int i = blockIdx.x * 256 + threadIdx.x;     // 4,864,000 float4 total, exact
    const float4 v = (i < 4352000) ? ((const float4*)value)[i]
                                   : ((const float4*)query)[i - 4352000];
    ushort4 o;
    o.x = f2bf(v.x); o.y = f2bf(v.y); o.z = f2bf(v.z); o.w = f2bf(v.w);
    ((ushort4*)out)[i] = o;
}

// ---------------- softmax + bilinear sampling, LP-SPLIT (512 thr) ----------------
// 1000 blocks x 512 threads; wave = 1 query. thread = (q8=tid>>6, half=(tid>>5)&1,
// h=(tid>>2)&7, oct=tid&3). half 0 samples levels 0-1, half 1 levels 2-3
// (32 gathers/thread); partials combine through padded LDS. XCD-swizzled.
__global__ __launch_bounds__(512) void ms_sample_split(
    const unsigned short* __restrict__ v,    // [BS,8500,256] bf16
    const float* __restrict__ offattn,       // [NQ,384]: offs[0:256) | logits[256:384)
    const float* __restrict__ refp,          // [NQ,4,2]
    unsigned short* __restrict__ out_pre)    // [NQ,256] bf16
{
    __shared__ float offx_s[8][16][8];
    __shared__ float offy_s[8][16][8];
    __shared__ float atw_s [8][16][8];
    __shared__ float ref_s [8][8];
    __shared__ float part  [8][32][9];       // [q][h*4+oct][ch], pad 9 vs 8

    const int tid  = threadIdx.x;
    const int bswz = blockIdx.x & 7;                       // batch -> XCD
    const int iq0  = bswz * 1000 + (blockIdx.x >> 3) * 8;  // 8 queries, same batch

    if (tid < 64) {
        const int q = tid >> 3, h = tid & 7;
        const float* rowp = offattn + (size_t)(iq0 + q) * 384;
        float lg[16];
        float m = -1e30f;
        #pragma unroll
        for (int i = 0; i < 16; ++i) { lg[i] = rowp[256 + h * 16 + i]; m = fmaxf(m, lg[i]); }
        float s = 0.f;
        #pragma unroll
        for (int i = 0; i < 16; ++i) { lg[i] = __expf(lg[i] - m); s += lg[i]; }
        const float inv = 1.f / s;
        #pragma unroll
        for (int i = 0; i < 16; ++i) atw_s[q][i][h] = lg[i] * inv;
        #pragma unroll
        for (int i = 0; i < 16; ++i) {
            offx_s[q][i][h] = rowp[(h * 16 + i) * 2 + 0];
            offy_s[q][i][h] = rowp[(h * 16 + i) * 2 + 1];
        }
        if (h == 0) {
            #pragma unroll
            for (int i = 0; i < 8; ++i) ref_s[q][i] = refp[(size_t)(iq0 + q) * 8 + i];
        }
    }
    __syncthreads();

    const int q8   = tid >> 6;
    const int half = (tid >> 5) & 1;
    const int sub  = tid & 31;
    const int h    = sub >> 2;
    const int oct  = sub & 3;

    float acc[8] = {0.f, 0.f, 0.f, 0.f, 0.f, 0.f, 0.f, 0.f};
    const unsigned short* vb = v + (size_t)bswz * LEN_V * 256 + h * 32 + oct * 8;
    const int Hs[4] = {80, 40, 20, 10};
    const int st[4] = {0, 6400, 8000, 8400};

    #pragma unroll
    for (int li = 0; li < 2; ++li) {
        const int lvl = half * 2 + li;
        const int W = Hs[lvl];
        const float bx = ref_s[q8][lvl * 2 + 0] * (float)W - 0.5f;
        const float by = ref_s[q8][lvl * 2 + 1] * (float)W - 0.5f;
        const unsigned short* vl = vb + (size_t)st[lvl] * 256;
        #pragma unroll
        for (int p = 0; p < NPT; ++p) {
            const int lp = lvl * 4 + p;
            const float x  = bx + offx_s[q8][lp][h];
            const float y  = by + offy_s[q8][lp][h];
            const float at = atw_s[q8][lp][h];
            const float x0f = floorf(x), y0f = floorf(y);
            const float fx = x - x0f, fy = y - y0f;
            const int x0 = (int)x0f, y0 = (int)y0f;
            const int x1 = x0 + 1,   y1 = y0 + 1;
            const int cx0 = min(max(x0, 0), W - 1);
            const int cx1 = min(max(x1, 0), W - 1);
            const int cy0 = min(max(y0, 0), W - 1);
            const int cy1 = min(max(y1, 0), W - 1);
            const float vx0 = (x0 >= 0 && x0 < W) ? 1.f : 0.f;
            const float vx1 = (x1 >= 0 && x1 < W) ? 1.f : 0.f;
            const float vy0 = (y0 >= 0 && y0 < W) ? 1.f : 0.f;
            const float vy1 = (y1 >= 0 && y1 < W) ? 1.f : 0.f;
            const float w00 = at * (1.f - fx) * (1.f - fy) * vx0 * vy0;
            const float w01 = at * fx * (1.f - fy) * vx1 * vy0;
            const float w10 = at * (1.f - fx) * fy * vx0 * vy1;
            const float w11 = at * fx * fy * vx1 * vy1;
            const unsigned short* r0 = vl + (size_t)(cy0 * W) * 256;
            const unsigned short* r1 = vl + (size_t)(cy1 * W) * 256;
            const uint4 d00 = *(const uint4*)(r0 + (size_t)cx0 * 256);
            const uint4 d01 = *(const uint4*)(r0 + (size_t)cx1 * 256);
            const uint4 d10 = *(const uint4*)(r1 + (size_t)cx0 * 256);
            const uint4 d11 = *(const uint4*)(r1 + (size_t)cx1 * 256);
            acc[0] += w00 * asf(d00.x << 16) + w01 * asf(d01.x << 16)
                    + w10 * asf(d10.x << 16) + w11 * asf(d11.x << 16);
            acc[1] += w00 * asf(d00.x & 0xffff0000u) + w01 * asf(d01.x & 0xffff0000u)
                    + w10 * asf(d10.x & 0xffff0000u) + w11 * asf(d11.x & 0xffff0000u);
            acc[2] += w00 * asf(d00.y << 16) + w01 * asf(d01.y << 16)
                    + w10 * asf(d10.y << 16) + w11 * asf(d11.y << 16);
            acc[3] += w00 * asf(d00.y & 0xffff0000u) + w01 * asf(d01.y & 0xffff0000u)
                    + w10 * asf(d10.y & 0xffff0000u) + w11 * asf(d11.y & 0xffff0000u);
            acc[4] += w00 * asf(d00.z << 16) + w01 * asf(d01.z << 16)
                    + w10 * asf(d10.z << 16) + w11 * asf(d11.z << 16);
            acc[5] += w00 * asf(d00.z & 0xffff0000u) + w01 * asf(d01.z & 0xffff0000u)
                    + w10 * asf(d10.z & 0xffff0000u) + w11 * asf(d11.z & 0xffff0000u);
            acc[6] += w00 * asf(d00.w << 16) + w01 * asf(d01.w << 16)
                    + w10 * asf(d10.w << 16) + w11 * asf(d11.w << 16);
            acc[7] += w00 * asf(d00.w & 0xffff0000u) + w01 * asf(d01.w & 0xffff0000u)
                    + w10 * asf(d10.w & 0xffff0000u) + w11 * asf(d11.w & 0xffff0000u);
        }
    }

    if (half == 1) {
        #pragma unroll
        for (int j = 0; j < 8; ++j) part[q8][sub][j] = acc[j];
    }
    __syncthreads();
    if (half == 0) {
        short8 o;
        #pragma unroll
        for (int j = 0; j < 8; ++j) o[j] = (short)f2bf(acc[j] + part[q8][sub][j]);
        *(short8*)(out_pre + (size_t)(iq0 + q8) * 256 + sub * 8) = o;
    }
}

// ------------------------------- launcher -------------------------------
extern "C" void kernel_launch(void* const* d_in, const int* in_sizes, int n_in,
                              void* d_out, int out_size, void* d_ws, size_t ws_size,
                              hipStream_t stream)
{
    const float* query  = (const float*)d_in[0];
    const float* refp   = (const float*)d_in[1];
    const float* value  = (const float*)d_in[2];
    const float* w_off  = (const float*)d_in[3];
    const float* b_off  = (const float*)d_in[4];
    const float* w_attn = (const float*)d_in[5];
    const float* b_attn = (const float*)d_in[6];
    const float* w_v    = (const float*)d_in[7];
    const float* b_v    = (const float*)d_in[8];
    const float* w_o    = (const float*)d_in[9];
    const float* b_o    = (const float*)d_in[10];
    (void)d_in[11]; (void)d_in[12];  // shapes/starts fixed by problem, hardcoded

    float* out = (float*)d_out;

    // workspace layout (bytes; end 86,474,752 == round-2's proven size).
    // out_pre ALIASES the head of valq_bf: value_bf is dead after the v-proj
    // GEMM completes (stream-ordered), and the sampler runs after it.
    char* ws = (char*)d_ws;
    unsigned short* valq_bf = (unsigned short*)ws;                    // 76000*256*2 = 38,912,000
    unsigned short* out_pre = (unsigned short*)ws;                    // 4,096,000 (alias, see above)
    unsigned short* v_proj  = (unsigned short*)(ws + 38912000);       // 34,816,000
    float*          offattn = (float*)(ws + 73728000);                // 12,288,000
    unsigned short* wv_f    = (unsigned short*)(ws + 86016000);       //    131,072
    unsigned short* woa_f   = (unsigned short*)(ws + 86147072);       //    196,608
    unsigned short* wo_f    = (unsigned short*)(ws + 86343680);       //    131,072

    dim3 blk(256);

    hipLaunchKernelGGL(wtransform, dim3(112), blk, 0, stream,
                       w_v, w_off, w_attn, w_o, wv_f, woa_f, wo_f);
    // value||query -> bf16 (4,864,000 float4)
    hipLaunchKernelGGL(cast2_bf16, dim3(19000), blk, 0, stream,
                       value, query, valq_bf);
    // v_proj = value_bf @ w_v + b_v  (bf16 out)  [68000 x 256], DMA pipeline
    hipLaunchKernelGGL((mfma_gemm_dma<true>), dim3(532, 2), blk, 0, stream,
                       valq_bf, wv_f, b_v, nullptr, 1 << 30, v_proj, MV);
    // offattn = query_bf @ [w_off | w_attn] + bias  (fp32 out)  [8000 x 384]
    hipLaunchKernelGGL((mfma_gemm_dma<false>), dim3(125, 3), blk, 0, stream,
                       valq_bf + (size_t)MV * 256, woa_f, b_off, b_attn, 256, offattn, NQ);
    // sampling + softmax (lp-split, 512 thr) -> out_pre bf16
    hipLaunchKernelGGL(ms_sample_split, dim3(1000), dim3(512), 0, stream,
                       v_proj, offattn, refp, out_pre);
    // out = out_pre @ w_o + b_o  [8000 x 256] fp32, DMA pipeline
    hipLaunchKernelGGL((mfma_gemm_dma<false>), dim3(125, 2), blk, 0, stream,
                       out_pre, wo_f, b_o, nullptr, 1 << 30, out, NQ);
}

// Round 10
// 194.095 us; speedup vs baseline: 1.3365x; 1.0395x over previous
//
#include <hip/hip_runtime.h>
#include <hip/hip_bf16.h>
#include <math.h>

// Problem constants (fixed by setup_inputs)
#define BS     8
#define LQ     1000
#define DMODEL 256
#define NH     8
#define NLV    4
#define NPT    4
#define LEN_V  8500          // 80*80+40*40+20*20+10*10
#define NQ     (BS*LQ)       // 8000
#define MV     (BS*LEN_V)    // 68000
#define KS     8             // K=256 / 32 per mfma step

typedef __attribute__((ext_vector_type(8))) short short8;     // 8 bf16 (4 VGPRs)
typedef __attribute__((ext_vector_type(4))) float floatx4;

static __device__ __forceinline__ unsigned short f2bf(float f) {
    __hip_bfloat16 h = __float2bfloat16(f);   // RNE
    return __builtin_bit_cast(unsigned short, h);
}
static __device__ __forceinline__ float asf(unsigned int u) {
    return __builtin_bit_cast(float, u);
}

// async global->LDS DMA, 16B per lane; LDS dest = wave-uniform base + lane*16
static __device__ __forceinline__ void dma16(const unsigned short* g, unsigned short* lds) {
    __builtin_amdgcn_global_load_lds(
        (const __attribute__((address_space(1))) unsigned int*)g,
        (__attribute__((address_space(3))) unsigned int*)lds,
        16, 0, 0);
}

// ---------------------------------------------------------------------------
// DMA double-buffered MFMA GEMM core (round-8 proven structure, runtime cfg).
//   A bf16 row-major staged via global_load_lds into 2x32KB LDS; source-side
//   XOR swizzle; DMA(t+1) overlaps K-loop(t); one barrier per tile.
// ---------------------------------------------------------------------------
static __device__ __forceinline__ void gemm_dma_core(
    const unsigned short* __restrict__ Ab, const unsigned short* __restrict__ Bfrag,
    const float* __restrict__ bias1, const float* __restrict__ bias2, int nsplit,
    void* __restrict__ Cptr, int M, int N, int bn, int bm_start, int bm_stride,
    bool outbf, unsigned short (*As)[16384])
{
    const int tid = threadIdx.x;
    const int l   = tid & 63;
    const int w   = tid >> 6;          // wave = column quarter (0..3)
    const int lm  = l & 15;
    const int lk  = l >> 4;
    const int x7  = lm & 7;
    const int n_mtiles = (M + 63) >> 6;

    short8 Bf[2][KS];
    const int u0 = bn * 8 + w * 2;
    #pragma unroll
    for (int j = 0; j < 2; ++j)
        #pragma unroll
        for (int s = 0; s < KS; ++s)
            Bf[j][s] = *(const short8*)(Bfrag + ((size_t)((u0 + j) * KS + s) * 64 + l) * 8);

    auto dma_tile = [&](int tile, int buf) {
        #pragma unroll
        for (int j = 0; j < 8; ++j) {                 // 8 * 256 lanes * 16B = 32KB
            const int slot = j * 256 + tid;
            const int row  = slot >> 5;
            const int gp   = slot & 31;               // physical chunk pos
            const int gc   = gp ^ (row & 7);          // logical chunk fetched here
            int grow = tile * 64 + row; grow = grow < M ? grow : M - 1;
            dma16(Ab + (size_t)grow * 256 + gc * 8,
                  &As[buf][(j * 256 + w * 64) * 8]);  // uniform base; HW adds lane*16
        }
    };

    int bm  = bm_start;
    int buf = 0;
    if (bm < n_mtiles) dma_tile(bm, 0);

    while (bm < n_mtiles) {
        const int bm_next = bm + bm_stride;

        __builtin_amdgcn_s_waitcnt(0);
        __syncthreads();
        if (bm_next < n_mtiles) dma_tile(bm_next, buf ^ 1);  // flies during K-loop

        floatx4 acc[4][2];
        #pragma unroll
        for (int i = 0; i < 4; ++i)
            #pragma unroll
            for (int j = 0; j < 2; ++j)
                #pragma unroll
                for (int r = 0; r < 4; ++r) acc[i][j][r] = 0.f;

        #pragma unroll
        for (int s = 0; s < KS; ++s) {
            short8 afr[4];
            #pragma unroll
            for (int i = 0; i < 4; ++i)
                afr[i] = *(const short8*)(
                    &As[buf][(i * 16 + lm) * 256 + (((s * 4 + lk) ^ x7)) * 8]);
            #pragma unroll
            for (int i = 0; i < 4; ++i)
                #pragma unroll
                for (int j = 0; j < 2; ++j)
                    acc[i][j] = __builtin_amdgcn_mfma_f32_16x16x32_bf16(
                                    afr[i], Bf[j][s], acc[i][j], 0, 0, 0);
        }

        #pragma unroll
        for (int j = 0; j < 2; ++j) {
            const int col = bn * 128 + w * 32 + j * 16 + lm;
            const float bv = (bias2 != nullptr && col >= nsplit) ? bias2[col - nsplit]
                                                                 : bias1[col];
            #pragma unroll
            for (int i = 0; i < 4; ++i) {
                const int rbase = bm * 64 + i * 16 + lk * 4;
                #pragma unroll
                for (int r = 0; r < 4; ++r) {
                    const int row = rbase + r;
                    if (row < M) {
                        const float v = acc[i][j][r] + bv;
                        if (outbf)
                            ((unsigned short*)Cptr)[(size_t)row * N + col] = f2bf(v);
                        else
                            ((float*)Cptr)[(size_t)row * N + col] = v;
                    }
                }
            }
        }

        buf ^= 1;
        bm = bm_next;
    }
}

// ---- fused independent GEMMs: v-proj (slots 0..1063) + offattn (1064..1438) ----
__global__ __launch_bounds__(256, 2) void gemm_fused(
    const unsigned short* __restrict__ valq_bf,
    const unsigned short* __restrict__ wv_f, const unsigned short* __restrict__ woa_f,
    const float* __restrict__ b_v, const float* __restrict__ b_off,
    const float* __restrict__ b_attn,
    unsigned short* __restrict__ v_proj, float* __restrict__ offattn)
{
    __shared__ unsigned short As[2][16384];
    int bx = blockIdx.x;
    if (bx < 1064) {
        const int bm0 = bx % 532, bn = bx / 532;
        gemm_dma_core(valq_bf, wv_f, b_v, nullptr, 1 << 30,
                      v_proj, MV, 256, bn, bm0, 532, true, As);
    } else {
        bx -= 1064;
        const int bm0 = bx % 125, bn = bx / 125;
        gemm_dma_core(valq_bf + (size_t)MV * 256, woa_f, b_off, b_attn, 256,
                      offattn, NQ, 384, bn, bm0, 125, false, As);
    }
}

// ---- out-projection GEMM: out = out_pre @ w_o + b_o ----
__global__ __launch_bounds__(256, 2) void gemm_out(
    const unsigned short* __restrict__ out_pre, const unsigned short* __restrict__ wo_f,
    const float* __restrict__ b_o, float* __restrict__ out)
{
    __shared__ unsigned short As[2][16384];
    gemm_dma_core(out_pre, wo_f, b_o, nullptr, 1 << 30,
                  out, NQ, 256, blockIdx.y, blockIdx.x, 125, false, As);
}

// ---- prep: value||query -> bf16 cast (blocks 0..18999) + weight transform ----
__global__ __launch_bounds__(256) void prep(
    const float* __restrict__ value, const float* __restrict__ query,
    unsigned short* __restrict__ valq_bf,
    const float* __restrict__ w_v, const float* __restrict__ w_off,
    const float* __restrict__ w_attn, const float* __restrict__ w_o,
    unsigned short* __restrict__ wv_f, unsigned short* __restrict__ woa_f,
    unsigned short* __restrict__ wo_f)
{
    const int bx = blockIdx.x;
    if (bx < 19000) {
        const int i = bx * 256 + threadIdx.x;         // 4,864,000 float4, exact
        const float4 v = (i < 4352000) ? ((const float4*)value)[i]
                                       : ((const float4*)query)[i - 4352000];
        ushort4 o;
        o.x = f2bf(v.x); o.y = f2bf(v.y); o.z = f2bf(v.z); o.w = f2bf(v.w);
        ((ushort4*)valq_bf)[i] = o;
    } else {
        const int gid = (bx - 19000) * 256 + threadIdx.x;   // 28672 total, exact
        int chunk, mode;
        if (gid < 8192)               { chunk = gid;         mode = 0; }
        else if (gid < 8192 + 12288)  { chunk = gid - 8192;  mode = 1; }
        else                          { chunk = gid - 20480; mode = 2; }
        const int l = chunk & 63, s = (chunk >> 6) & 7, u = chunk >> 9;
        short8 o;
        #pragma unroll
        for (int j = 0; j < 8; ++j) {
            const int k = s * 32 + (l >> 4) * 8 + j;
            const int n = u * 16 + (l & 15);
            float v;
            if (mode == 0)      v = w_v[k * 256 + n];
            else if (mode == 1) v = (n < 256) ? w_off[k * 256 + n] : w_attn[k * 128 + (n - 256)];
            else                v = w_o[k * 256 + n];
            o[j] = (short)f2bf(v);
        }
        unsigned short* dp = (mode == 0 ? wv_f : mode == 1 ? woa_f : wo_f)
                             + ((size_t)(u * 8 + s) * 64 + l) * 8;
        *(short8*)dp = o;
    }
}

// ---------------- softmax + bilinear sampling, LP-SPLIT (512 thr) ----------------
// 1000 blocks x 512 threads; wave = 1 query. half 0 samples levels 0-1, half 1
// levels 2-3 (32 gathers/thread); partials combine through padded LDS.
__global__ __launch_bounds__(512) void ms_sample_split(
    const unsigned short* __restrict__ v,    // [BS,8500,256] bf16
    const float* __restrict__ offattn,       // [NQ,384]: offs[0:256) | logits[256:384)
    const float* __restrict__ refp,          // [NQ,4,2]
    unsigned short* __restrict__ out_pre)    // [NQ,256] bf16
{
    __shared__ float offx_s[8][16][8];
    __shared__ float offy_s[8][16][8];
    __shared__ float atw_s [8][16][8];
    __shared__ float ref_s [8][8];
    __shared__ float part  [8][32][9];       // [q][h*4+oct][ch], pad 9 vs 8

    const int tid  = threadIdx.x;
    const int bswz = blockIdx.x & 7;                       // batch -> XCD
    const int iq0  = bswz * 1000 + (blockIdx.x >> 3) * 8;  // 8 queries, same batch

    if (tid < 64) {
        const int q = tid >> 3, h = tid & 7;
        const float* rowp = offattn + (size_t)(iq0 + q) * 384;
        float lg[16];
        float m = -1e30f;
        #pragma unroll
        for (int i = 0; i < 16; ++i) { lg[i] = rowp[256 + h * 16 + i]; m = fmaxf(m, lg[i]); }
        float s = 0.f;
        #pragma unroll
        for (int i = 0; i < 16; ++i) { lg[i] = __expf(lg[i] - m); s += lg[i]; }
        const float inv = 1.f / s;
        #pragma unroll
        for (int i = 0; i < 16; ++i) atw_s[q][i][h] = lg[i] * inv;
        #pragma unroll
        for (int i = 0; i < 16; ++i) {
            offx_s[q][i][h] = rowp[(h * 16 + i) * 2 + 0];
            offy_s[q][i][h] = rowp[(h * 16 + i) * 2 + 1];
        }
        if (h == 0) {
            #pragma unroll
            for (int i = 0; i < 8; ++i) ref_s[q][i] = refp[(size_t)(iq0 + q) * 8 + i];
        }
    }
    __syncthreads();

    const int q8   = tid >> 6;
    const int half = (tid >> 5) & 1;
    const int sub  = tid & 31;
    const int h    = sub >> 2;
    const int oct  = sub & 3;

    float acc[8] = {0.f, 0.f, 0.f, 0.f, 0.f, 0.f, 0.f, 0.f};
    const unsigned short* vb = v + (size_t)bswz * LEN_V * 256 + h * 32 + oct * 8;
    const int Hs[4] = {80, 40, 20, 10};
    const int st[4] = {0, 6400, 8000, 8400};

    #pragma unroll
    for (int li = 0; li < 2; ++li) {
        const int lvl = half * 2 + li;
        const int W = Hs[lvl];
        const float bx = ref_s[q8][lvl * 2 + 0] * (float)W - 0.5f;
        const float by = ref_s[q8][lvl * 2 + 1] * (float)W - 0.5f;
        const unsigned short* vl = vb + (size_t)st[lvl] * 256;
        #pragma unroll
        for (int p = 0; p < NPT; ++p) {
            const int lp = lvl * 4 + p;
            const float x  = bx + offx_s[q8][lp][h];
            const float y  = by + offy_s[q8][lp][h];
            const float at = atw_s[q8][lp][h];
            const float x0f = floorf(x), y0f = floorf(y);
            const float fx = x - x0f, fy = y - y0f;
            const int x0 = (int)x0f, y0 = (int)y0f;
            const int x1 = x0 + 1,   y1 = y0 + 1;
            const int cx0 = min(max(x0, 0), W - 1);
            const int cx1 = min(max(x1, 0), W - 1);
            const int cy0 = min(max(y0, 0), W - 1);
            const int cy1 = min(max(y1, 0), W - 1);
            const float vx0 = (x0 >= 0 && x0 < W) ? 1.f : 0.f;
            const float vx1 = (x1 >= 0 && x1 < W) ? 1.f : 0.f;
            const float vy0 = (y0 >= 0 && y0 < W) ? 1.f : 0.f;
            const float vy1 = (y1 >= 0 && y1 < W) ? 1.f : 0.f;
            const float w00 = at * (1.f - fx) * (1.f - fy) * vx0 * vy0;
            const float w01 = at * fx * (1.f - fy) * vx1 * vy0;
            const float w10 = at * (1.f - fx) * fy * vx0 * vy1;
            const float w11 = at * fx * fy * vx1 * vy1;
            const unsigned short* r0 = vl + (size_t)(cy0 * W) * 256;
            const unsigned short* r1 = vl + (size_t)(cy1 * W) * 256;
            const uint4 d00 = *(const uint4*)(r0 + (size_t)cx0 * 256);
            const uint4 d01 = *(const uint4*)(r0 + (size_t)cx1 * 256);
            const uint4 d10 = *(const uint4*)(r1 + (size_t)cx0 * 256);
            const uint4 d11 = *(const uint4*)(r1 + (size_t)cx1 * 256);
            acc[0] += w00 * asf(d00.x << 16) + w01 * asf(d01.x << 16)
                    + w10 * asf(d10.x << 16) + w11 * asf(d11.x << 16);
            acc[1] += w00 * asf(d00.x & 0xffff0000u) + w01 * asf(d01.x & 0xffff0000u)
                    + w10 * asf(d10.x & 0xffff0000u) + w11 * asf(d11.x & 0xffff0000u);
            acc[2] += w00 * asf(d00.y << 16) + w01 * asf(d01.y << 16)
                    + w10 * asf(d10.y << 16) + w11 * asf(d11.y << 16);
            acc[3] += w00 * asf(d00.y & 0xffff0000u) + w01 * asf(d01.y & 0xffff0000u)
                    + w10 * asf(d10.y & 0xffff0000u) + w11 * asf(d11.y & 0xffff0000u);
            acc[4] += w00 * asf(d00.z << 16) + w01 * asf(d01.z << 16)
                    + w10 * asf(d10.z << 16) + w11 * asf(d11.z << 16);
            acc[5] += w00 * asf(d00.z & 0xffff0000u) + w01 * asf(d01.z & 0xffff0000u)
                    + w10 * asf(d10.z & 0xffff0000u) + w11 * asf(d11.z & 0xffff0000u);
            acc[6] += w00 * asf(d00.w << 16) + w01 * asf(d01.w << 16)
                    + w10 * asf(d10.w << 16) + w11 * asf(d11.w << 16);
            acc[7] += w00 * asf(d00.w & 0xffff0000u) + w01 * asf(d01.w & 0xffff0000u)
                    + w10 * asf(d10.w & 0xffff0000u) + w11 * asf(d11.w & 0xffff0000u);
        }
    }

    if (half == 1) {
        #pragma unroll
        for (int j = 0; j < 8; ++j) part[q8][sub][j] = acc[j];
    }
    __syncthreads();
    if (half == 0) {
        short8 o;
        #pragma unroll
        for (int j = 0; j < 8; ++j) o[j] = (short)f2bf(acc[j] + part[q8][sub][j]);
        *(short8*)(out_pre + (size_t)(iq0 + q8) * 256 + sub * 8) = o;
    }
}

// ------------------------------- launcher -------------------------------
extern "C" void kernel_launch(void* const* d_in, const int* in_sizes, int n_in,
                              void* d_out, int out_size, void* d_ws, size_t ws_size,
                              hipStream_t stream)
{
    const float* query  = (const float*)d_in[0];
    const float* refp   = (const float*)d_in[1];
    const float* value  = (const float*)d_in[2];
    const float* w_off  = (const float*)d_in[3];
    const float* b_off  = (const float*)d_in[4];
    const float* w_attn = (const float*)d_in[5];
    const float* b_attn = (const float*)d_in[6];
    const float* w_v    = (const float*)d_in[7];
    const float* b_v    = (const float*)d_in[8];
    const float* w_o    = (const float*)d_in[9];
    const float* b_o    = (const float*)d_in[10];
    (void)d_in[11]; (void)d_in[12];  // shapes/starts fixed by problem, hardcoded

    float* out = (float*)d_out;

    // workspace layout (bytes; end 86,474,752 == round-2's proven size).
    // out_pre ALIASES valq_bf: value/query bf16 are dead once both fused GEMMs
    // finish (stream-ordered before the sampler writes out_pre).
    char* ws = (char*)d_ws;
    unsigned short* valq_bf = (unsigned short*)ws;                    // 38,912,000
    unsigned short* out_pre = (unsigned short*)ws;                    //  4,096,000 (alias)
    unsigned short* v_proj  = (unsigned short*)(ws + 38912000);       // 34,816,000
    float*          offattn = (float*)(ws + 73728000);                // 12,288,000
    unsigned short* wv_f    = (unsigned short*)(ws + 86016000);       //    131,072
    unsigned short* woa_f   = (unsigned short*)(ws + 86147072);       //    196,608
    unsigned short* wo_f    = (unsigned short*)(ws + 86343680);       //    131,072

    dim3 blk(256);

    // 1) casts + weight transforms (19112 blocks)
    hipLaunchKernelGGL(prep, dim3(19112), blk, 0, stream,
                       value, query, valq_bf, w_v, w_off, w_attn, w_o,
                       wv_f, woa_f, wo_f);
    // 2) v-proj + offattn in one launch (1439 block slots)
    hipLaunchKernelGGL(gemm_fused, dim3(1439), blk, 0, stream,
                       valq_bf, wv_f, woa_f, b_v, b_off, b_attn, v_proj, offattn);
    // 3) sampling + softmax (lp-split, 512 thr) -> out_pre bf16
    hipLaunchKernelGGL(ms_sample_split, dim3(1000), dim3(512), 0, stream,
                       v_proj, offattn, refp, out_pre);
    // 4) out = out_pre @ w_o + b_o  [8000 x 256] fp32
    hipLaunchKernelGGL(gemm_out, dim3(125, 2), blk, 0, stream,
                       out_pre, wo_f, b_o, out);
}